// Round 2
// baseline (3634.322 us; speedup 1.0000x reference)
//
#include <hip/hip_runtime.h>

#define NPTS   1000000
#define KSTEPS 32
#define NF     8
#define IMG_H  1024
#define IMG_W  1024
#define FID    1000
#define HW     (IMG_H * IMG_W)
#define MAXREP 8

// ---------------------------------------------------------------------------
// Pass 1: iterate points, accumulate into HWC-interleaved replica buffers in
// d_ws. 4 channel atomics per hit land in one aligned 16B segment (1 line).
// Replica index = blockIdx % R spreads hot-pixel contention.
// ---------------------------------------------------------------------------
__global__ __launch_bounds__(256) void flame_accum_kernel(
    const float* __restrict__ palette,
    const float* __restrict__ Amat,
    const float* __restrict__ bvec,
    const float* __restrict__ fcolor,
    const float* __restrict__ xy0,
    const float* __restrict__ c0,
    const float* __restrict__ minv,
    const float* __restrict__ rangev,
    const int*   __restrict__ fn_idx,
    const int*   __restrict__ skipk_ptr,
    float*       __restrict__ ws,      // [R][HW][4] interleaved
    int R)
{
    __shared__ __align__(16) float s_pal[FID * 4];
    __shared__ float s_A[NF * 4];
    __shared__ float s_b[NF * 2];
    __shared__ float s_fc[NF];

    for (int t = threadIdx.x; t < FID; t += 256)
        ((float4*)s_pal)[t] = ((const float4*)palette)[t];
    if (threadIdx.x < NF * 4) s_A[threadIdx.x] = Amat[threadIdx.x];
    if (threadIdx.x < NF * 2) s_b[threadIdx.x] = bvec[threadIdx.x];
    if (threadIdx.x < NF)     s_fc[threadIdx.x] = fcolor[threadIdx.x];
    __syncthreads();

    const int i = blockIdx.x * 256 + threadIdx.x;
    if (i >= NPTS) return;

    float* __restrict__ acc = ws + (size_t)(blockIdx.x % R) * HW * 4;

    const int   skipk = skipk_ptr[0];
    const float minx = minv[0], miny = minv[1];
    const float rx   = rangev[0], ry = rangev[1];

    const float2 xyv = ((const float2*)xy0)[i];
    float x = xyv.x, y = xyv.y;
    float c = c0[i];

    for (int k = 0; k < KSTEPS; ++k) {
        const int idx = fn_idx[(size_t)k * NPTS + i];

        // xy = A[idx] @ xy + b[idx]   (numpy semantics: no FMA contraction)
        const float a00 = s_A[idx * 4 + 0], a01 = s_A[idx * 4 + 1];
        const float a10 = s_A[idx * 4 + 2], a11 = s_A[idx * 4 + 3];
        const float b0  = s_b[idx * 2 + 0], b1  = s_b[idx * 2 + 1];
        const float nx = __fadd_rn(__fadd_rn(__fmul_rn(a00, x), __fmul_rn(a01, y)), b0);
        const float ny = __fadd_rn(__fadd_rn(__fmul_rn(a10, x), __fmul_rn(a11, y)), b1);
        x = nx; y = ny;

        // c = (c + fcolor[idx]) * 0.5
        c = __fmul_rn(__fadd_rn(c, s_fc[idx]), 0.5f);

        // bins = ((xy - min_vec) * range_vec).astype(int32)  (trunc toward 0)
        const int xb = (int)__fmul_rn(__fsub_rn(x, minx), rx);
        const int yb = (int)__fmul_rn(__fsub_rn(y, miny), ry);

        const bool inb = (xb >= 0) & (xb < IMG_W) & (yb >= 0) & (yb < IMG_H) & (k >= skipk);
        if (inb) {
            int pi = (int)__fadd_rn(__fmul_rn(c, 999.0f), 0.0005f);
            pi = min(max(pi, 0), FID - 1);
            const float4 col = *(const float4*)&s_pal[pi * 4];

            float* p = acc + ((size_t)xb * IMG_W + yb) * 4;
            atomicAdd(p + 0, col.x);
            atomicAdd(p + 1, col.y);
            atomicAdd(p + 2, col.z);
            atomicAdd(p + 3, col.w);
        }
    }
}

// ---------------------------------------------------------------------------
// Pass 2: reduce replicas, transpose HWC -> CHW, add raw_image, write d_out.
// ---------------------------------------------------------------------------
__global__ __launch_bounds__(256) void reduce_kernel(
    const float* __restrict__ ws,
    const float* __restrict__ raw_image,
    float*       __restrict__ out,
    int R)
{
    const int p = blockIdx.x * 256 + threadIdx.x;
    if (p >= HW) return;

    float4 acc = make_float4(0.f, 0.f, 0.f, 0.f);
    for (int r = 0; r < R; ++r) {
        const float4 v = *(const float4*)(ws + ((size_t)r * HW + p) * 4);
        acc.x += v.x; acc.y += v.y; acc.z += v.z; acc.w += v.w;
    }
    out[0 * (size_t)HW + p] = raw_image[0 * (size_t)HW + p] + acc.x;
    out[1 * (size_t)HW + p] = raw_image[1 * (size_t)HW + p] + acc.y;
    out[2 * (size_t)HW + p] = raw_image[2 * (size_t)HW + p] + acc.z;
    out[3 * (size_t)HW + p] = raw_image[3 * (size_t)HW + p] + acc.w;
}

// ---------------------------------------------------------------------------
// Fallback (tiny/absent ws): direct CHW atomics into d_out, as in round 1.
// ---------------------------------------------------------------------------
__global__ __launch_bounds__(256) void flame_direct_kernel(
    const float* __restrict__ palette,
    const float* __restrict__ Amat,
    const float* __restrict__ bvec,
    const float* __restrict__ fcolor,
    const float* __restrict__ xy0,
    const float* __restrict__ c0,
    const float* __restrict__ minv,
    const float* __restrict__ rangev,
    const int*   __restrict__ fn_idx,
    const int*   __restrict__ skipk_ptr,
    float*       __restrict__ img)
{
    __shared__ __align__(16) float s_pal[FID * 4];
    __shared__ float s_A[NF * 4];
    __shared__ float s_b[NF * 2];
    __shared__ float s_fc[NF];

    for (int t = threadIdx.x; t < FID; t += 256)
        ((float4*)s_pal)[t] = ((const float4*)palette)[t];
    if (threadIdx.x < NF * 4) s_A[threadIdx.x] = Amat[threadIdx.x];
    if (threadIdx.x < NF * 2) s_b[threadIdx.x] = bvec[threadIdx.x];
    if (threadIdx.x < NF)     s_fc[threadIdx.x] = fcolor[threadIdx.x];
    __syncthreads();

    const int i = blockIdx.x * 256 + threadIdx.x;
    if (i >= NPTS) return;

    const int   skipk = skipk_ptr[0];
    const float minx = minv[0], miny = minv[1];
    const float rx   = rangev[0], ry = rangev[1];

    const float2 xyv = ((const float2*)xy0)[i];
    float x = xyv.x, y = xyv.y;
    float c = c0[i];

    for (int k = 0; k < KSTEPS; ++k) {
        const int idx = fn_idx[(size_t)k * NPTS + i];
        const float a00 = s_A[idx * 4 + 0], a01 = s_A[idx * 4 + 1];
        const float a10 = s_A[idx * 4 + 2], a11 = s_A[idx * 4 + 3];
        const float b0  = s_b[idx * 2 + 0], b1  = s_b[idx * 2 + 1];
        const float nx = __fadd_rn(__fadd_rn(__fmul_rn(a00, x), __fmul_rn(a01, y)), b0);
        const float ny = __fadd_rn(__fadd_rn(__fmul_rn(a10, x), __fmul_rn(a11, y)), b1);
        x = nx; y = ny;
        c = __fmul_rn(__fadd_rn(c, s_fc[idx]), 0.5f);
        const int xb = (int)__fmul_rn(__fsub_rn(x, minx), rx);
        const int yb = (int)__fmul_rn(__fsub_rn(y, miny), ry);
        const bool inb = (xb >= 0) & (xb < IMG_W) & (yb >= 0) & (yb < IMG_H) & (k >= skipk);
        if (inb) {
            int pi = (int)__fadd_rn(__fmul_rn(c, 999.0f), 0.0005f);
            pi = min(max(pi, 0), FID - 1);
            const float4 col = *(const float4*)&s_pal[pi * 4];
            const size_t base = (size_t)xb * IMG_W + yb;
            atomicAdd(&img[base + 0 * (size_t)HW], col.x);
            atomicAdd(&img[base + 1 * (size_t)HW], col.y);
            atomicAdd(&img[base + 2 * (size_t)HW], col.z);
            atomicAdd(&img[base + 3 * (size_t)HW], col.w);
        }
    }
}

extern "C" void kernel_launch(void* const* d_in, const int* in_sizes, int n_in,
                              void* d_out, int out_size, void* d_ws, size_t ws_size,
                              hipStream_t stream) {
    const float* raw_image = (const float*)d_in[0];
    const float* palette   = (const float*)d_in[1];
    const float* A         = (const float*)d_in[2];
    const float* b         = (const float*)d_in[3];
    const float* fcolor    = (const float*)d_in[4];
    const float* xy0       = (const float*)d_in[5];
    const float* c0        = (const float*)d_in[6];
    const float* minv      = (const float*)d_in[7];
    const float* rangev    = (const float*)d_in[8];
    const int*   fn_idx    = (const int*)d_in[9];
    const int*   skipk     = (const int*)d_in[10];
    float* img = (float*)d_out;

    const size_t rep_bytes = (size_t)HW * 4 * sizeof(float);   // 16 MB
    int R = (int)(ws_size / rep_bytes);
    if (R > MAXREP) R = MAXREP;

    const dim3 grid_pts((NPTS + 255) / 256);

    if (R >= 1) {
        hipMemsetAsync(d_ws, 0, (size_t)R * rep_bytes, stream);
        flame_accum_kernel<<<grid_pts, 256, 0, stream>>>(
            palette, A, b, fcolor, xy0, c0, minv, rangev, fn_idx, skipk,
            (float*)d_ws, R);
        reduce_kernel<<<dim3((HW + 255) / 256), 256, 0, stream>>>(
            (const float*)d_ws, raw_image, img, R);
    } else {
        hipMemcpyAsync(img, raw_image, (size_t)out_size * sizeof(float),
                       hipMemcpyDeviceToDevice, stream);
        flame_direct_kernel<<<grid_pts, 256, 0, stream>>>(
            palette, A, b, fcolor, xy0, c0, minv, rangev, fn_idx, skipk, img);
    }
}

// Round 3
// 1604.777 us; speedup vs baseline: 2.2647x; 2.2647x over previous
//
#include <hip/hip_runtime.h>

#define NPTS   1000000
#define KSTEPS 32
#define NF     8
#define IMG_H  1024
#define IMG_W  1024
#define FID    1000
#define HW     (IMG_H * IMG_W)

// Fixed-point scale for packed accumulation: 22 fractional bits.
// Palette channels are in [0,1); per-pixel channel sums are ~<=40 (max ref
// value ~18), so a 32-bit field (capacity 2^10 = 1024.0) cannot overflow,
// and quantization error is <=2^-23 per hit (~1e-5 per pixel total).
#define FPSCALE 4194304.0f   // 2^22
#define FPINV   (1.0f / 4194304.0f)

// ---------------------------------------------------------------------------
// Pass 1: iterate points; accumulate into ws as [HW][2] uint64:
//   word0 = ch0 | ch1<<32,  word1 = ch2 | ch3<<32   (fixed point)
// 2 atomics per hit instead of 4.
// ---------------------------------------------------------------------------
__global__ __launch_bounds__(256) void flame_accum_packed(
    const float* __restrict__ palette,
    const float* __restrict__ Amat,
    const float* __restrict__ bvec,
    const float* __restrict__ fcolor,
    const float* __restrict__ xy0,
    const float* __restrict__ c0,
    const float* __restrict__ minv,
    const float* __restrict__ rangev,
    const int*   __restrict__ fn_idx,
    const int*   __restrict__ skipk_ptr,
    unsigned long long* __restrict__ ws)
{
    __shared__ __align__(16) float s_pal[FID * 4];
    __shared__ float s_A[NF * 4];
    __shared__ float s_b[NF * 2];
    __shared__ float s_fc[NF];

    for (int t = threadIdx.x; t < FID; t += 256)
        ((float4*)s_pal)[t] = ((const float4*)palette)[t];
    if (threadIdx.x < NF * 4) s_A[threadIdx.x] = Amat[threadIdx.x];
    if (threadIdx.x < NF * 2) s_b[threadIdx.x] = bvec[threadIdx.x];
    if (threadIdx.x < NF)     s_fc[threadIdx.x] = fcolor[threadIdx.x];
    __syncthreads();

    const int i = blockIdx.x * 256 + threadIdx.x;
    if (i >= NPTS) return;

    const int   skipk = skipk_ptr[0];
    const float minx = minv[0], miny = minv[1];
    const float rx   = rangev[0], ry = rangev[1];

    const float2 xyv = ((const float2*)xy0)[i];
    float x = xyv.x, y = xyv.y;
    float c = c0[i];

    for (int k = 0; k < KSTEPS; ++k) {
        const int idx = fn_idx[(size_t)k * NPTS + i];

        // xy = A[idx] @ xy + b[idx]  (numpy semantics: no FMA contraction —
        // this exact op sequence decides bin assignment; do not change it)
        const float a00 = s_A[idx * 4 + 0], a01 = s_A[idx * 4 + 1];
        const float a10 = s_A[idx * 4 + 2], a11 = s_A[idx * 4 + 3];
        const float b0  = s_b[idx * 2 + 0], b1  = s_b[idx * 2 + 1];
        const float nx = __fadd_rn(__fadd_rn(__fmul_rn(a00, x), __fmul_rn(a01, y)), b0);
        const float ny = __fadd_rn(__fadd_rn(__fmul_rn(a10, x), __fmul_rn(a11, y)), b1);
        x = nx; y = ny;

        // c = (c + fcolor[idx]) * 0.5
        c = __fmul_rn(__fadd_rn(c, s_fc[idx]), 0.5f);

        // bins = ((xy - min_vec) * range_vec).astype(int32)  (trunc toward 0)
        const int xb = (int)__fmul_rn(__fsub_rn(x, minx), rx);
        const int yb = (int)__fmul_rn(__fsub_rn(y, miny), ry);

        const bool inb = (xb >= 0) & (xb < IMG_W) & (yb >= 0) & (yb < IMG_H) & (k >= skipk);
        if (inb) {
            int pi = (int)__fadd_rn(__fmul_rn(c, 999.0f), 0.0005f);
            pi = min(max(pi, 0), FID - 1);
            const float4 col = *(const float4*)&s_pal[pi * 4];

            const unsigned u0 = __float2uint_rn(__fmul_rn(col.x, FPSCALE));
            const unsigned u1 = __float2uint_rn(__fmul_rn(col.y, FPSCALE));
            const unsigned u2 = __float2uint_rn(__fmul_rn(col.z, FPSCALE));
            const unsigned u3 = __float2uint_rn(__fmul_rn(col.w, FPSCALE));
            const unsigned long long w0 =
                (unsigned long long)u0 | ((unsigned long long)u1 << 32);
            const unsigned long long w1 =
                (unsigned long long)u2 | ((unsigned long long)u3 << 32);

            unsigned long long* p = ws + ((size_t)xb * IMG_W + yb) * 2;
            atomicAdd(p + 0, w0);
            atomicAdd(p + 1, w1);
        }
    }
}

// ---------------------------------------------------------------------------
// Pass 2: unpack fixed point, transpose HWC -> CHW, add raw_image, write out.
// ---------------------------------------------------------------------------
__global__ __launch_bounds__(256) void reduce_packed(
    const unsigned long long* __restrict__ ws,
    const float* __restrict__ raw_image,
    float*       __restrict__ out)
{
    const int p = blockIdx.x * 256 + threadIdx.x;
    if (p >= HW) return;

    const unsigned long long w0 = ws[(size_t)p * 2 + 0];
    const unsigned long long w1 = ws[(size_t)p * 2 + 1];
    const float s0 = (float)(unsigned)(w0 & 0xffffffffull) * FPINV;
    const float s1 = (float)(unsigned)(w0 >> 32)           * FPINV;
    const float s2 = (float)(unsigned)(w1 & 0xffffffffull) * FPINV;
    const float s3 = (float)(unsigned)(w1 >> 32)           * FPINV;

    out[0 * (size_t)HW + p] = raw_image[0 * (size_t)HW + p] + s0;
    out[1 * (size_t)HW + p] = raw_image[1 * (size_t)HW + p] + s1;
    out[2 * (size_t)HW + p] = raw_image[2 * (size_t)HW + p] + s2;
    out[3 * (size_t)HW + p] = raw_image[3 * (size_t)HW + p] + s3;
}

// ---------------------------------------------------------------------------
// Fallback (ws too small): direct CHW f32 atomics into d_out (round-1 path).
// ---------------------------------------------------------------------------
__global__ __launch_bounds__(256) void flame_direct_kernel(
    const float* __restrict__ palette,
    const float* __restrict__ Amat,
    const float* __restrict__ bvec,
    const float* __restrict__ fcolor,
    const float* __restrict__ xy0,
    const float* __restrict__ c0,
    const float* __restrict__ minv,
    const float* __restrict__ rangev,
    const int*   __restrict__ fn_idx,
    const int*   __restrict__ skipk_ptr,
    float*       __restrict__ img)
{
    __shared__ __align__(16) float s_pal[FID * 4];
    __shared__ float s_A[NF * 4];
    __shared__ float s_b[NF * 2];
    __shared__ float s_fc[NF];

    for (int t = threadIdx.x; t < FID; t += 256)
        ((float4*)s_pal)[t] = ((const float4*)palette)[t];
    if (threadIdx.x < NF * 4) s_A[threadIdx.x] = Amat[threadIdx.x];
    if (threadIdx.x < NF * 2) s_b[threadIdx.x] = bvec[threadIdx.x];
    if (threadIdx.x < NF)     s_fc[threadIdx.x] = fcolor[threadIdx.x];
    __syncthreads();

    const int i = blockIdx.x * 256 + threadIdx.x;
    if (i >= NPTS) return;

    const int   skipk = skipk_ptr[0];
    const float minx = minv[0], miny = minv[1];
    const float rx   = rangev[0], ry = rangev[1];

    const float2 xyv = ((const float2*)xy0)[i];
    float x = xyv.x, y = xyv.y;
    float c = c0[i];

    for (int k = 0; k < KSTEPS; ++k) {
        const int idx = fn_idx[(size_t)k * NPTS + i];
        const float a00 = s_A[idx * 4 + 0], a01 = s_A[idx * 4 + 1];
        const float a10 = s_A[idx * 4 + 2], a11 = s_A[idx * 4 + 3];
        const float b0  = s_b[idx * 2 + 0], b1  = s_b[idx * 2 + 1];
        const float nx = __fadd_rn(__fadd_rn(__fmul_rn(a00, x), __fmul_rn(a01, y)), b0);
        const float ny = __fadd_rn(__fadd_rn(__fmul_rn(a10, x), __fmul_rn(a11, y)), b1);
        x = nx; y = ny;
        c = __fmul_rn(__fadd_rn(c, s_fc[idx]), 0.5f);
        const int xb = (int)__fmul_rn(__fsub_rn(x, minx), rx);
        const int yb = (int)__fmul_rn(__fsub_rn(y, miny), ry);
        const bool inb = (xb >= 0) & (xb < IMG_W) & (yb >= 0) & (yb < IMG_H) & (k >= skipk);
        if (inb) {
            int pi = (int)__fadd_rn(__fmul_rn(c, 999.0f), 0.0005f);
            pi = min(max(pi, 0), FID - 1);
            const float4 col = *(const float4*)&s_pal[pi * 4];
            const size_t base = (size_t)xb * IMG_W + yb;
            atomicAdd(&img[base + 0 * (size_t)HW], col.x);
            atomicAdd(&img[base + 1 * (size_t)HW], col.y);
            atomicAdd(&img[base + 2 * (size_t)HW], col.z);
            atomicAdd(&img[base + 3 * (size_t)HW], col.w);
        }
    }
}

extern "C" void kernel_launch(void* const* d_in, const int* in_sizes, int n_in,
                              void* d_out, int out_size, void* d_ws, size_t ws_size,
                              hipStream_t stream) {
    const float* raw_image = (const float*)d_in[0];
    const float* palette   = (const float*)d_in[1];
    const float* A         = (const float*)d_in[2];
    const float* b         = (const float*)d_in[3];
    const float* fcolor    = (const float*)d_in[4];
    const float* xy0       = (const float*)d_in[5];
    const float* c0        = (const float*)d_in[6];
    const float* minv      = (const float*)d_in[7];
    const float* rangev    = (const float*)d_in[8];
    const int*   fn_idx    = (const int*)d_in[9];
    const int*   skipk     = (const int*)d_in[10];
    float* img = (float*)d_out;

    const size_t need = (size_t)HW * 2 * sizeof(unsigned long long);  // 16 MB

    const dim3 grid_pts((NPTS + 255) / 256);

    if (ws_size >= need) {
        hipMemsetAsync(d_ws, 0, need, stream);
        flame_accum_packed<<<grid_pts, 256, 0, stream>>>(
            palette, A, b, fcolor, xy0, c0, minv, rangev, fn_idx, skipk,
            (unsigned long long*)d_ws);
        reduce_packed<<<dim3((HW + 255) / 256), 256, 0, stream>>>(
            (const unsigned long long*)d_ws, raw_image, img);
    } else {
        hipMemcpyAsync(img, raw_image, (size_t)out_size * sizeof(float),
                       hipMemcpyDeviceToDevice, stream);
        flame_direct_kernel<<<grid_pts, 256, 0, stream>>>(
            palette, A, b, fcolor, xy0, c0, minv, rangev, fn_idx, skipk, img);
    }
}

// Round 4
// 289.743 us; speedup vs baseline: 12.5432x; 5.5386x over previous
//
#include <hip/hip_runtime.h>

typedef unsigned int u32;
typedef unsigned long long u64;

#define NPTS   1000000
#define KSTEPS 32
#define NF     8
#define IMG_H  1024
#define IMG_W  1024
#define FID    1000
#define HW     (IMG_H * IMG_W)
#define NB     3907            // ceil(NPTS/256)
#define NBKT   256             // bucket = pixel >> 12  (4 image rows)
#define BKTPX  4096            // pixels per bucket
#define K5G    768             // accumulate workgroups (>= 256 + 508)
#define FPSCALE 4194304.0f     // 2^22 fixed point; capacity 1024 > max sum 488
#define FPINV   (1.0f / 4194304.0f)

// One chaos-game step, numpy-exact (no FMA contraction). Updates x,y,c and
// sets xb,yb,inb. Requires s_A/s_b/s_fc, minx/miny/rx/ry, skipk in scope.
#define FLAME_STEP(IDX, K)                                                     \
  {                                                                            \
    const float a00 = s_A[(IDX)*4+0], a01 = s_A[(IDX)*4+1];                    \
    const float a10 = s_A[(IDX)*4+2], a11 = s_A[(IDX)*4+3];                    \
    const float b0  = s_b[(IDX)*2+0], b1  = s_b[(IDX)*2+1];                    \
    const float nx = __fadd_rn(__fadd_rn(__fmul_rn(a00,x),__fmul_rn(a01,y)),b0);\
    const float ny = __fadd_rn(__fadd_rn(__fmul_rn(a10,x),__fmul_rn(a11,y)),b1);\
    x = nx; y = ny;                                                            \
    c = __fmul_rn(__fadd_rn(c, s_fc[IDX]), 0.5f);                              \
    xb = (int)__fmul_rn(__fsub_rn(x, minx), rx);                               \
    yb = (int)__fmul_rn(__fsub_rn(y, miny), ry);                               \
    inb = (xb >= 0) & (xb < IMG_W) & (yb >= 0) & (yb < IMG_H) & ((K) >= skipk);\
  }

#define LOAD_TABLES()                                                          \
    if (threadIdx.x < NF * 4) s_A[threadIdx.x]  = Amat[threadIdx.x];           \
    if (threadIdx.x < NF * 2) s_b[threadIdx.x]  = bvec[threadIdx.x];           \
    if (threadIdx.x < NF)     s_fc[threadIdx.x] = fcolor[threadIdx.x];

// ---------------------------------------------------------------------------
// K1a: per-(block,bucket) hit counts. counts[blk][bkt], no global atomics.
// ---------------------------------------------------------------------------
__global__ __launch_bounds__(256) void k_count(
    const float* __restrict__ Amat, const float* __restrict__ bvec,
    const float* __restrict__ fcolor,
    const float* __restrict__ xy0, const float* __restrict__ c0,
    const float* __restrict__ minv, const float* __restrict__ rangev,
    const int* __restrict__ fn_idx, const int* __restrict__ skipk_ptr,
    u32* __restrict__ counts)
{
    __shared__ u32 s_cnt[NBKT];
    __shared__ float s_A[NF*4]; __shared__ float s_b[NF*2]; __shared__ float s_fc[NF];
    s_cnt[threadIdx.x] = 0u;
    LOAD_TABLES();
    __syncthreads();

    const int i = blockIdx.x * 256 + threadIdx.x;
    if (i < NPTS) {
        const int   skipk = skipk_ptr[0];
        const float minx = minv[0], miny = minv[1];
        const float rx = rangev[0], ry = rangev[1];
        const float2 xyv = ((const float2*)xy0)[i];
        float x = xyv.x, y = xyv.y, c = c0[i];
        #pragma unroll
        for (int k = 0; k < KSTEPS; ++k) {
            const int idx = fn_idx[(size_t)k * NPTS + i];
            int xb, yb; bool inb;
            FLAME_STEP(idx, k);
            if (inb) atomicAdd(&s_cnt[xb >> 2], 1u);
        }
    }
    __syncthreads();
    counts[(size_t)blockIdx.x * NBKT + threadIdx.x] = s_cnt[threadIdx.x];
}

// ---------------------------------------------------------------------------
// K2a: per-bucket exclusive prefix over blocks; totals per bucket.
// grid = 256 (one wg per bucket), 256 threads, 16 rows/thread.
// ---------------------------------------------------------------------------
__global__ __launch_bounds__(256) void k_scanblocks(
    const u32* __restrict__ counts, u32* __restrict__ prefix,
    u32* __restrict__ totals)
{
    const int b = blockIdx.x, tid = threadIdx.x;
    u32 v[16]; u32 s = 0;
    #pragma unroll
    for (int j = 0; j < 16; ++j) {
        const int row = tid * 16 + j;
        v[j] = (row < NB) ? counts[(size_t)row * NBKT + b] : 0u;
        s += v[j];
    }
    __shared__ u32 sc[256];
    sc[tid] = s; __syncthreads();
    #pragma unroll
    for (int o = 1; o < 256; o <<= 1) {
        u32 t = (tid >= o) ? sc[tid - o] : 0u;
        __syncthreads();
        sc[tid] += t;
        __syncthreads();
    }
    u32 run = sc[tid] - s;   // exclusive
    #pragma unroll
    for (int j = 0; j < 16; ++j) {
        const int row = tid * 16 + j;
        if (row < NB) prefix[(size_t)row * NBKT + b] = run;
        run += v[j];
    }
    if (tid == 255) totals[b] = sc[255];
}

// ---------------------------------------------------------------------------
// K2b: bucket bases (scan of totals), chunk assignment m[b], wstart scan,
// and fixed-point palette conversion. Single workgroup.
// ---------------------------------------------------------------------------
__global__ __launch_bounds__(256) void k_meta(
    const float* __restrict__ palette,
    const u32* __restrict__ totals,
    u32* __restrict__ bases, u32* __restrict__ mm, u32* __restrict__ wstart,
    u32* __restrict__ pal_u32)
{
    __shared__ u32 sc[256];
    const int tid = threadIdx.x;

    for (int t = tid; t < FID * 4; t += 256)
        pal_u32[t] = __float2uint_rn(__fmul_rn(palette[t], FPSCALE));

    const u32 t0 = totals[tid];
    sc[tid] = t0; __syncthreads();
    #pragma unroll
    for (int o = 1; o < 256; o <<= 1) {
        u32 v = (tid >= o) ? sc[tid - o] : 0u;
        __syncthreads(); sc[tid] += v; __syncthreads();
    }
    const u32 total = sc[255];
    bases[tid] = sc[tid] - t0;

    const u32 m = 1u + (total ? (u32)((508ull * t0) / total) : 0u);
    mm[tid] = m;
    __syncthreads(); sc[tid] = m; __syncthreads();
    #pragma unroll
    for (int o = 1; o < 256; o <<= 1) {
        u32 v = (tid >= o) ? sc[tid - o] : 0u;
        __syncthreads(); sc[tid] += v; __syncthreads();
    }
    wstart[tid] = sc[tid] - m;
    if (tid == 255) wstart[256] = sc[255];
}

// ---------------------------------------------------------------------------
// K1b: re-iterate, emit records (pixel<<10 | pal) into bucketed regions.
// Cursor per bucket = bases[b] + prefix[blk][b]; zero global atomics.
// ---------------------------------------------------------------------------
__global__ __launch_bounds__(256) void k_emit(
    const float* __restrict__ Amat, const float* __restrict__ bvec,
    const float* __restrict__ fcolor,
    const float* __restrict__ xy0, const float* __restrict__ c0,
    const float* __restrict__ minv, const float* __restrict__ rangev,
    const int* __restrict__ fn_idx, const int* __restrict__ skipk_ptr,
    const u32* __restrict__ prefix, const u32* __restrict__ bases,
    u32* __restrict__ records)
{
    __shared__ u32 s_cur[NBKT];
    __shared__ float s_A[NF*4]; __shared__ float s_b[NF*2]; __shared__ float s_fc[NF];
    s_cur[threadIdx.x] = bases[threadIdx.x] +
                         prefix[(size_t)blockIdx.x * NBKT + threadIdx.x];
    LOAD_TABLES();
    __syncthreads();

    const int i = blockIdx.x * 256 + threadIdx.x;
    if (i < NPTS) {
        const int   skipk = skipk_ptr[0];
        const float minx = minv[0], miny = minv[1];
        const float rx = rangev[0], ry = rangev[1];
        const float2 xyv = ((const float2*)xy0)[i];
        float x = xyv.x, y = xyv.y, c = c0[i];
        u32 rec[KSTEPS];
        #pragma unroll
        for (int k = 0; k < KSTEPS; ++k) {
            const int idx = fn_idx[(size_t)k * NPTS + i];
            int xb, yb; bool inb;
            FLAME_STEP(idx, k);
            u32 r = 0xFFFFFFFFu;
            if (inb) {
                int pi = (int)__fadd_rn(__fmul_rn(c, 999.0f), 0.0005f);
                pi = min(max(pi, 0), FID - 1);
                r = (((u32)(xb << 10 | yb)) << 10) | (u32)pi;
            }
            rec[k] = r;
        }
        #pragma unroll
        for (int k = 0; k < KSTEPS; ++k) {
            const u32 r = rec[k];
            if (r != 0xFFFFFFFFu) {
                const u32 bkt = r >> 22;
                const u32 pos = atomicAdd(&s_cur[bkt], 1u);
                records[pos] = r;
            }
        }
    }
}

// ---------------------------------------------------------------------------
// K5: per-chunk LDS tile accumulation (ds_add_u32 fixed point), write partial.
// ---------------------------------------------------------------------------
__global__ __launch_bounds__(256) void k_accum(
    const u32* __restrict__ pal_u32,
    const u32* __restrict__ totals, const u32* __restrict__ bases,
    const u32* __restrict__ mm, const u32* __restrict__ wstart,
    const u32* __restrict__ records,
    u32* __restrict__ partials)
{
    __shared__ u32 tile[BKTPX * 4];     // 64 KB
    __shared__ u32 s_ws[NBKT + 1];
    const int tid = threadIdx.x, w = blockIdx.x;

    s_ws[tid] = wstart[tid];
    if (tid == 0) s_ws[NBKT] = wstart[NBKT];
    __syncthreads();
    if ((u32)w >= s_ws[NBKT]) return;   // uniform per block

    // largest b with wstart[b] <= w
    int b = 0;
    #pragma unroll
    for (int step = 128; step; step >>= 1)
        if (b + step <= 255 && s_ws[b + step] <= (u32)w) b += step;

    for (int t = tid; t < BKTPX * 4; t += 256) tile[t] = 0u;
    __syncthreads();

    const u32 cnt = totals[b], m = mm[b], cch = (u32)w - s_ws[b];
    const u32 rs = bases[b] + (u32)(((u64)cnt * cch) / m);
    const u32 re = bases[b] + (u32)(((u64)cnt * (cch + 1)) / m);

    for (u32 j = rs + tid; j < re; j += 256) {
        const u32 r = records[j];
        const u32 local = (r >> 10) & 4095u;
        const u32 pal = r & 1023u;
        const uint4 pc = ((const uint4*)pal_u32)[pal];
        atomicAdd(&tile[local * 4 + 0], pc.x);
        atomicAdd(&tile[local * 4 + 1], pc.y);
        atomicAdd(&tile[local * 4 + 2], pc.z);
        atomicAdd(&tile[local * 4 + 3], pc.w);
    }
    __syncthreads();

    uint4* dst = (uint4*)(partials + (size_t)w * BKTPX * 4);
    const uint4* src = (const uint4*)tile;
    for (int t = tid; t < BKTPX; t += 256) dst[t] = src[t];
}

// ---------------------------------------------------------------------------
// K6: sum partial tiles per bucket, unpack, add raw_image, write CHW out.
// ---------------------------------------------------------------------------
__global__ __launch_bounds__(256) void k_final(
    const u32* __restrict__ partials, const u32* __restrict__ wstart,
    const float* __restrict__ raw, float* __restrict__ out)
{
    const int p = blockIdx.x * 256 + threadIdx.x;
    const int b = p >> 12, local = p & 4095;
    u32 a0 = 0, a1 = 0, a2 = 0, a3 = 0;
    const u32 w0 = wstart[b], w1 = wstart[b + 1];
    for (u32 w = w0; w < w1; ++w) {
        const uint4 v = ((const uint4*)partials)[(size_t)w * BKTPX + local];
        a0 += v.x; a1 += v.y; a2 += v.z; a3 += v.w;
    }
    out[0*(size_t)HW + p] = __fadd_rn(raw[0*(size_t)HW + p], __fmul_rn((float)a0, FPINV));
    out[1*(size_t)HW + p] = __fadd_rn(raw[1*(size_t)HW + p], __fmul_rn((float)a1, FPINV));
    out[2*(size_t)HW + p] = __fadd_rn(raw[2*(size_t)HW + p], __fmul_rn((float)a2, FPINV));
    out[3*(size_t)HW + p] = __fadd_rn(raw[3*(size_t)HW + p], __fmul_rn((float)a3, FPINV));
}

// ---------------------------------------------------------------------------
// Fallback (round-3 path): packed u64 global atomics.
// ---------------------------------------------------------------------------
__global__ __launch_bounds__(256) void flame_accum_packed(
    const float* __restrict__ palette,
    const float* __restrict__ Amat, const float* __restrict__ bvec,
    const float* __restrict__ fcolor,
    const float* __restrict__ xy0, const float* __restrict__ c0,
    const float* __restrict__ minv, const float* __restrict__ rangev,
    const int* __restrict__ fn_idx, const int* __restrict__ skipk_ptr,
    u64* __restrict__ ws)
{
    __shared__ __align__(16) float s_pal[FID * 4];
    __shared__ float s_A[NF*4]; __shared__ float s_b[NF*2]; __shared__ float s_fc[NF];
    for (int t = threadIdx.x; t < FID; t += 256)
        ((float4*)s_pal)[t] = ((const float4*)palette)[t];
    LOAD_TABLES();
    __syncthreads();

    const int i = blockIdx.x * 256 + threadIdx.x;
    if (i >= NPTS) return;
    const int   skipk = skipk_ptr[0];
    const float minx = minv[0], miny = minv[1];
    const float rx = rangev[0], ry = rangev[1];
    const float2 xyv = ((const float2*)xy0)[i];
    float x = xyv.x, y = xyv.y, c = c0[i];

    for (int k = 0; k < KSTEPS; ++k) {
        const int idx = fn_idx[(size_t)k * NPTS + i];
        int xb, yb; bool inb;
        FLAME_STEP(idx, k);
        if (inb) {
            int pi = (int)__fadd_rn(__fmul_rn(c, 999.0f), 0.0005f);
            pi = min(max(pi, 0), FID - 1);
            const float4 col = *(const float4*)&s_pal[pi * 4];
            const u32 u0 = __float2uint_rn(__fmul_rn(col.x, FPSCALE));
            const u32 u1 = __float2uint_rn(__fmul_rn(col.y, FPSCALE));
            const u32 u2 = __float2uint_rn(__fmul_rn(col.z, FPSCALE));
            const u32 u3 = __float2uint_rn(__fmul_rn(col.w, FPSCALE));
            u64* p = ws + ((size_t)xb * IMG_W + yb) * 2;
            atomicAdd(p + 0, (u64)u0 | ((u64)u1 << 32));
            atomicAdd(p + 1, (u64)u2 | ((u64)u3 << 32));
        }
    }
}

__global__ __launch_bounds__(256) void reduce_packed(
    const u64* __restrict__ ws, const float* __restrict__ raw_image,
    float* __restrict__ out)
{
    const int p = blockIdx.x * 256 + threadIdx.x;
    if (p >= HW) return;
    const u64 w0 = ws[(size_t)p * 2 + 0];
    const u64 w1 = ws[(size_t)p * 2 + 1];
    out[0*(size_t)HW+p] = raw_image[0*(size_t)HW+p] + (float)(u32)(w0 & 0xffffffffull) * FPINV;
    out[1*(size_t)HW+p] = raw_image[1*(size_t)HW+p] + (float)(u32)(w0 >> 32)           * FPINV;
    out[2*(size_t)HW+p] = raw_image[2*(size_t)HW+p] + (float)(u32)(w1 & 0xffffffffull) * FPINV;
    out[3*(size_t)HW+p] = raw_image[3*(size_t)HW+p] + (float)(u32)(w1 >> 32)           * FPINV;
}

extern "C" void kernel_launch(void* const* d_in, const int* in_sizes, int n_in,
                              void* d_out, int out_size, void* d_ws, size_t ws_size,
                              hipStream_t stream) {
    const float* raw_image = (const float*)d_in[0];
    const float* palette   = (const float*)d_in[1];
    const float* A         = (const float*)d_in[2];
    const float* b         = (const float*)d_in[3];
    const float* fcolor    = (const float*)d_in[4];
    const float* xy0       = (const float*)d_in[5];
    const float* c0        = (const float*)d_in[6];
    const float* minv      = (const float*)d_in[7];
    const float* rangev    = (const float*)d_in[8];
    const int*   fn_idx    = (const int*)d_in[9];
    const int*   skipk     = (const int*)d_in[10];
    float* img = (float*)d_out;

    // ws layout (u32 units)
    u32* ws = (u32*)d_ws;
    u32* counts   = ws;                                  // NB*256
    u32* prefix   = counts + (size_t)NB * NBKT;          // NB*256
    u32* totals   = prefix + (size_t)NB * NBKT;          // 256
    u32* bases    = totals + 256;                        // 256
    u32* mm       = bases + 256;                         // 256
    u32* wstart   = mm + 256;                            // 257
    u32* pal_u32  = wstart + 512;                        // 4096 (aligned slack)
    u32* records  = pal_u32 + 4096;                      // NPTS*KSTEPS
    u32* partials = records + (size_t)NPTS * KSTEPS;     // K5G*BKTPX*4
    const size_t need_u32 = (size_t)(partials - ws) + (size_t)K5G * BKTPX * 4;
    const size_t NEED = need_u32 * sizeof(u32);          // ~186 MB

    if (ws_size >= NEED) {
        k_count<<<dim3(NB), 256, 0, stream>>>(A, b, fcolor, xy0, c0, minv,
                                              rangev, fn_idx, skipk, counts);
        k_scanblocks<<<dim3(NBKT), 256, 0, stream>>>(counts, prefix, totals);
        k_meta<<<dim3(1), 256, 0, stream>>>(palette, totals, bases, mm, wstart,
                                            pal_u32);
        k_emit<<<dim3(NB), 256, 0, stream>>>(A, b, fcolor, xy0, c0, minv,
                                             rangev, fn_idx, skipk, prefix,
                                             bases, records);
        k_accum<<<dim3(K5G), 256, 0, stream>>>(pal_u32, totals, bases, mm,
                                               wstart, records, partials);
        k_final<<<dim3(HW / 256), 256, 0, stream>>>(partials, wstart,
                                                    raw_image, img);
    } else {
        // round-3 fallback: packed u64 atomics
        const size_t need2 = (size_t)HW * 2 * sizeof(u64);
        hipMemsetAsync(d_ws, 0, need2, stream);
        flame_accum_packed<<<dim3(NB), 256, 0, stream>>>(
            palette, A, b, fcolor, xy0, c0, minv, rangev, fn_idx, skipk,
            (u64*)d_ws);
        reduce_packed<<<dim3((HW + 255) / 256), 256, 0, stream>>>(
            (const u64*)d_ws, raw_image, img);
    }
}

// Round 5
// 269.204 us; speedup vs baseline: 13.5003x; 1.0763x over previous
//
#include <hip/hip_runtime.h>

typedef unsigned int u32;
typedef unsigned long long u64;

#define NPTS   1000000
#define KSTEPS 32
#define NF     8
#define IMG_H  1024
#define IMG_W  1024
#define FID    1000
#define HW     (IMG_H * IMG_W)
#define NB     3907            // ceil(NPTS/256)
#define NBKT   256             // bucket = pixel >> 12  (4 image rows)
#define BKTPX  4096            // pixels per bucket
#define K5G    768             // accumulate workgroups (>= 256 + 508)
#define FPSCALE 4194304.0f     // 2^22 fixed point; capacity 1024 > max sum 488
#define FPINV   (1.0f / 4194304.0f)

// One chaos-game step, numpy-exact (no FMA contraction). Updates x,y,c and
// sets xb,yb,inb. Requires s_A/s_b/s_fc, minx/miny/rx/ry, skipk in scope.
#define FLAME_STEP(IDX, K)                                                     \
  {                                                                            \
    const float a00 = s_A[(IDX)*4+0], a01 = s_A[(IDX)*4+1];                    \
    const float a10 = s_A[(IDX)*4+2], a11 = s_A[(IDX)*4+3];                    \
    const float b0  = s_b[(IDX)*2+0], b1  = s_b[(IDX)*2+1];                    \
    const float nx = __fadd_rn(__fadd_rn(__fmul_rn(a00,x),__fmul_rn(a01,y)),b0);\
    const float ny = __fadd_rn(__fadd_rn(__fmul_rn(a10,x),__fmul_rn(a11,y)),b1);\
    x = nx; y = ny;                                                            \
    c = __fmul_rn(__fadd_rn(c, s_fc[IDX]), 0.5f);                              \
    xb = (int)__fmul_rn(__fsub_rn(x, minx), rx);                               \
    yb = (int)__fmul_rn(__fsub_rn(y, miny), ry);                               \
    inb = (xb >= 0) & (xb < IMG_W) & (yb >= 0) & (yb < IMG_H) & ((K) >= skipk);\
  }

#define LOAD_TABLES()                                                          \
    if (threadIdx.x < NF * 4) s_A[threadIdx.x]  = Amat[threadIdx.x];           \
    if (threadIdx.x < NF * 2) s_b[threadIdx.x]  = bvec[threadIdx.x];           \
    if (threadIdx.x < NF)     s_fc[threadIdx.x] = fcolor[threadIdx.x];

// Preload ALL 32 fn_idx values (independent addresses) so the wave has 32
// loads in flight instead of a serial latency chain. Full unroll keeps the
// array in registers (static indices only).
#define PRELOAD_IDX()                                                          \
    int pidx[KSTEPS];                                                          \
    _Pragma("unroll")                                                          \
    for (int k = 0; k < KSTEPS; ++k) pidx[k] = fn_idx[(size_t)k * NPTS + i];

// ---------------------------------------------------------------------------
// K1a: per-(block,bucket) hit counts. counts[blk][bkt], no global atomics.
// ---------------------------------------------------------------------------
__global__ __launch_bounds__(256) void k_count(
    const float* __restrict__ Amat, const float* __restrict__ bvec,
    const float* __restrict__ fcolor,
    const float* __restrict__ xy0, const float* __restrict__ c0,
    const float* __restrict__ minv, const float* __restrict__ rangev,
    const int* __restrict__ fn_idx, const int* __restrict__ skipk_ptr,
    u32* __restrict__ counts)
{
    __shared__ u32 s_cnt[NBKT];
    __shared__ float s_A[NF*4]; __shared__ float s_b[NF*2]; __shared__ float s_fc[NF];
    s_cnt[threadIdx.x] = 0u;
    LOAD_TABLES();
    __syncthreads();

    const int i = blockIdx.x * 256 + threadIdx.x;
    if (i < NPTS) {
        const int   skipk = skipk_ptr[0];
        const float minx = minv[0], miny = minv[1];
        const float rx = rangev[0], ry = rangev[1];
        const float2 xyv = ((const float2*)xy0)[i];
        float x = xyv.x, y = xyv.y, c = c0[i];
        PRELOAD_IDX();
        #pragma unroll
        for (int k = 0; k < KSTEPS; ++k) {
            const int idx = pidx[k];
            int xb, yb; bool inb;
            FLAME_STEP(idx, k);
            if (inb) atomicAdd(&s_cnt[xb >> 2], 1u);
        }
    }
    __syncthreads();
    counts[(size_t)blockIdx.x * NBKT + threadIdx.x] = s_cnt[threadIdx.x];
}

// ---------------------------------------------------------------------------
// K2a: per-bucket exclusive prefix over blocks; totals per bucket.
// ---------------------------------------------------------------------------
__global__ __launch_bounds__(256) void k_scanblocks(
    const u32* __restrict__ counts, u32* __restrict__ prefix,
    u32* __restrict__ totals)
{
    const int b = blockIdx.x, tid = threadIdx.x;
    u32 v[16]; u32 s = 0;
    #pragma unroll
    for (int j = 0; j < 16; ++j) {
        const int row = tid * 16 + j;
        v[j] = (row < NB) ? counts[(size_t)row * NBKT + b] : 0u;
        s += v[j];
    }
    __shared__ u32 sc[256];
    sc[tid] = s; __syncthreads();
    #pragma unroll
    for (int o = 1; o < 256; o <<= 1) {
        u32 t = (tid >= o) ? sc[tid - o] : 0u;
        __syncthreads();
        sc[tid] += t;
        __syncthreads();
    }
    u32 run = sc[tid] - s;   // exclusive
    #pragma unroll
    for (int j = 0; j < 16; ++j) {
        const int row = tid * 16 + j;
        if (row < NB) prefix[(size_t)row * NBKT + b] = run;
        run += v[j];
    }
    if (tid == 255) totals[b] = sc[255];
}

// ---------------------------------------------------------------------------
// K2b: bucket bases, chunk counts m[b], wstart scan, fixed-point palette.
// ---------------------------------------------------------------------------
__global__ __launch_bounds__(256) void k_meta(
    const float* __restrict__ palette,
    const u32* __restrict__ totals,
    u32* __restrict__ bases, u32* __restrict__ mm, u32* __restrict__ wstart,
    u32* __restrict__ pal_u32)
{
    __shared__ u32 sc[256];
    const int tid = threadIdx.x;

    for (int t = tid; t < FID * 4; t += 256)
        pal_u32[t] = __float2uint_rn(__fmul_rn(palette[t], FPSCALE));

    const u32 t0 = totals[tid];
    sc[tid] = t0; __syncthreads();
    #pragma unroll
    for (int o = 1; o < 256; o <<= 1) {
        u32 v = (tid >= o) ? sc[tid - o] : 0u;
        __syncthreads(); sc[tid] += v; __syncthreads();
    }
    const u32 total = sc[255];
    bases[tid] = sc[tid] - t0;

    const u32 m = 1u + (total ? (u32)((508ull * t0) / total) : 0u);
    mm[tid] = m;
    __syncthreads(); sc[tid] = m; __syncthreads();
    #pragma unroll
    for (int o = 1; o < 256; o <<= 1) {
        u32 v = (tid >= o) ? sc[tid - o] : 0u;
        __syncthreads(); sc[tid] += v; __syncthreads();
    }
    wstart[tid] = sc[tid] - m;
    if (tid == 255) wstart[256] = sc[255];
}

// ---------------------------------------------------------------------------
// K1b: re-iterate, emit records (pixel<<10 | pal) into bucketed regions.
// Single fused loop (no rec[] scratch array), preloaded fn_idx.
// ---------------------------------------------------------------------------
__global__ __launch_bounds__(256) void k_emit(
    const float* __restrict__ Amat, const float* __restrict__ bvec,
    const float* __restrict__ fcolor,
    const float* __restrict__ xy0, const float* __restrict__ c0,
    const float* __restrict__ minv, const float* __restrict__ rangev,
    const int* __restrict__ fn_idx, const int* __restrict__ skipk_ptr,
    const u32* __restrict__ prefix, const u32* __restrict__ bases,
    u32* __restrict__ records)
{
    __shared__ u32 s_cur[NBKT];
    __shared__ float s_A[NF*4]; __shared__ float s_b[NF*2]; __shared__ float s_fc[NF];
    s_cur[threadIdx.x] = bases[threadIdx.x] +
                         prefix[(size_t)blockIdx.x * NBKT + threadIdx.x];
    LOAD_TABLES();
    __syncthreads();

    const int i = blockIdx.x * 256 + threadIdx.x;
    if (i < NPTS) {
        const int   skipk = skipk_ptr[0];
        const float minx = minv[0], miny = minv[1];
        const float rx = rangev[0], ry = rangev[1];
        const float2 xyv = ((const float2*)xy0)[i];
        float x = xyv.x, y = xyv.y, c = c0[i];
        PRELOAD_IDX();
        #pragma unroll
        for (int k = 0; k < KSTEPS; ++k) {
            const int idx = pidx[k];
            int xb, yb; bool inb;
            FLAME_STEP(idx, k);
            if (inb) {
                int pi = (int)__fadd_rn(__fmul_rn(c, 999.0f), 0.0005f);
                pi = min(max(pi, 0), FID - 1);
                const u32 r = (((u32)(xb << 10 | yb)) << 10) | (u32)pi;
                const u32 pos = atomicAdd(&s_cur[r >> 22], 1u);
                records[pos] = r;
            }
        }
    }
}

// ---------------------------------------------------------------------------
// K5: per-chunk LDS tile accumulation. Channels packed 2-per-u64 ds_add:
// 2 LDS atomics per record instead of 4 (2^22 fixed point, capacity 1024).
// ---------------------------------------------------------------------------
__global__ __launch_bounds__(256) void k_accum(
    const u32* __restrict__ pal_u32,
    const u32* __restrict__ totals, const u32* __restrict__ bases,
    const u32* __restrict__ mm, const u32* __restrict__ wstart,
    const u32* __restrict__ records,
    u32* __restrict__ partials)
{
    __shared__ u64 tile[BKTPX * 2];     // 64 KB
    __shared__ u32 s_ws[NBKT + 1];
    const int tid = threadIdx.x, w = blockIdx.x;

    s_ws[tid] = wstart[tid];
    if (tid == 0) s_ws[NBKT] = wstart[NBKT];
    __syncthreads();
    if ((u32)w >= s_ws[NBKT]) return;   // uniform per block

    // largest b with wstart[b] <= w
    int b = 0;
    #pragma unroll
    for (int step = 128; step; step >>= 1)
        if (b + step <= 255 && s_ws[b + step] <= (u32)w) b += step;

    for (int t = tid; t < BKTPX * 2; t += 256) tile[t] = 0ull;
    __syncthreads();

    const u32 cnt = totals[b], m = mm[b], cch = (u32)w - s_ws[b];
    const u32 rs = bases[b] + (u32)(((u64)cnt * cch) / m);
    const u32 re = bases[b] + (u32)(((u64)cnt * (cch + 1)) / m);

    const u64* pal_u64 = (const u64*)pal_u32;
    for (u32 j = rs + tid; j < re; j += 256) {
        const u32 r = records[j];
        const u32 local = (r >> 10) & 4095u;
        const u32 pal = r & 1023u;
        const u64 w0 = pal_u64[pal * 2 + 0];
        const u64 w1 = pal_u64[pal * 2 + 1];
        atomicAdd(&tile[local * 2 + 0], w0);
        atomicAdd(&tile[local * 2 + 1], w1);
    }
    __syncthreads();

    uint4* dst = (uint4*)(partials + (size_t)w * BKTPX * 4);
    const uint4* src = (const uint4*)tile;
    for (int t = tid; t < BKTPX; t += 256) dst[t] = src[t];
}

// ---------------------------------------------------------------------------
// K6: sum partial tiles per bucket, unpack, add raw_image, write CHW out.
// ---------------------------------------------------------------------------
__global__ __launch_bounds__(256) void k_final(
    const u32* __restrict__ partials, const u32* __restrict__ wstart,
    const float* __restrict__ raw, float* __restrict__ out)
{
    const int p = blockIdx.x * 256 + threadIdx.x;
    const int b = p >> 12, local = p & 4095;
    u32 a0 = 0, a1 = 0, a2 = 0, a3 = 0;
    const u32 w0 = wstart[b], w1 = wstart[b + 1];
    for (u32 w = w0; w < w1; ++w) {
        const uint4 v = ((const uint4*)partials)[(size_t)w * BKTPX + local];
        a0 += v.x; a1 += v.y; a2 += v.z; a3 += v.w;
    }
    out[0*(size_t)HW + p] = __fadd_rn(raw[0*(size_t)HW + p], __fmul_rn((float)a0, FPINV));
    out[1*(size_t)HW + p] = __fadd_rn(raw[1*(size_t)HW + p], __fmul_rn((float)a1, FPINV));
    out[2*(size_t)HW + p] = __fadd_rn(raw[2*(size_t)HW + p], __fmul_rn((float)a2, FPINV));
    out[3*(size_t)HW + p] = __fadd_rn(raw[3*(size_t)HW + p], __fmul_rn((float)a3, FPINV));
}

// ---------------------------------------------------------------------------
// Fallback (round-3 path): packed u64 global atomics.
// ---------------------------------------------------------------------------
__global__ __launch_bounds__(256) void flame_accum_packed(
    const float* __restrict__ palette,
    const float* __restrict__ Amat, const float* __restrict__ bvec,
    const float* __restrict__ fcolor,
    const float* __restrict__ xy0, const float* __restrict__ c0,
    const float* __restrict__ minv, const float* __restrict__ rangev,
    const int* __restrict__ fn_idx, const int* __restrict__ skipk_ptr,
    u64* __restrict__ ws)
{
    __shared__ __align__(16) float s_pal[FID * 4];
    __shared__ float s_A[NF*4]; __shared__ float s_b[NF*2]; __shared__ float s_fc[NF];
    for (int t = threadIdx.x; t < FID; t += 256)
        ((float4*)s_pal)[t] = ((const float4*)palette)[t];
    LOAD_TABLES();
    __syncthreads();

    const int i = blockIdx.x * 256 + threadIdx.x;
    if (i >= NPTS) return;
    const int   skipk = skipk_ptr[0];
    const float minx = minv[0], miny = minv[1];
    const float rx = rangev[0], ry = rangev[1];
    const float2 xyv = ((const float2*)xy0)[i];
    float x = xyv.x, y = xyv.y, c = c0[i];
    PRELOAD_IDX();
    #pragma unroll
    for (int k = 0; k < KSTEPS; ++k) {
        const int idx = pidx[k];
        int xb, yb; bool inb;
        FLAME_STEP(idx, k);
        if (inb) {
            int pi = (int)__fadd_rn(__fmul_rn(c, 999.0f), 0.0005f);
            pi = min(max(pi, 0), FID - 1);
            const float4 col = *(const float4*)&s_pal[pi * 4];
            const u32 u0 = __float2uint_rn(__fmul_rn(col.x, FPSCALE));
            const u32 u1 = __float2uint_rn(__fmul_rn(col.y, FPSCALE));
            const u32 u2 = __float2uint_rn(__fmul_rn(col.z, FPSCALE));
            const u32 u3 = __float2uint_rn(__fmul_rn(col.w, FPSCALE));
            u64* p = ws + ((size_t)xb * IMG_W + yb) * 2;
            atomicAdd(p + 0, (u64)u0 | ((u64)u1 << 32));
            atomicAdd(p + 1, (u64)u2 | ((u64)u3 << 32));
        }
    }
}

__global__ __launch_bounds__(256) void reduce_packed(
    const u64* __restrict__ ws, const float* __restrict__ raw_image,
    float* __restrict__ out)
{
    const int p = blockIdx.x * 256 + threadIdx.x;
    if (p >= HW) return;
    const u64 w0 = ws[(size_t)p * 2 + 0];
    const u64 w1 = ws[(size_t)p * 2 + 1];
    out[0*(size_t)HW+p] = raw_image[0*(size_t)HW+p] + (float)(u32)(w0 & 0xffffffffull) * FPINV;
    out[1*(size_t)HW+p] = raw_image[1*(size_t)HW+p] + (float)(u32)(w0 >> 32)           * FPINV;
    out[2*(size_t)HW+p] = raw_image[2*(size_t)HW+p] + (float)(u32)(w1 & 0xffffffffull) * FPINV;
    out[3*(size_t)HW+p] = raw_image[3*(size_t)HW+p] + (float)(u32)(w1 >> 32)           * FPINV;
}

extern "C" void kernel_launch(void* const* d_in, const int* in_sizes, int n_in,
                              void* d_out, int out_size, void* d_ws, size_t ws_size,
                              hipStream_t stream) {
    const float* raw_image = (const float*)d_in[0];
    const float* palette   = (const float*)d_in[1];
    const float* A         = (const float*)d_in[2];
    const float* b         = (const float*)d_in[3];
    const float* fcolor    = (const float*)d_in[4];
    const float* xy0       = (const float*)d_in[5];
    const float* c0        = (const float*)d_in[6];
    const float* minv      = (const float*)d_in[7];
    const float* rangev    = (const float*)d_in[8];
    const int*   fn_idx    = (const int*)d_in[9];
    const int*   skipk     = (const int*)d_in[10];
    float* img = (float*)d_out;

    // ws layout (u32 units)
    u32* ws = (u32*)d_ws;
    u32* counts   = ws;                                  // NB*256
    u32* prefix   = counts + (size_t)NB * NBKT;          // NB*256
    u32* totals   = prefix + (size_t)NB * NBKT;          // 256
    u32* bases    = totals + 256;                        // 256
    u32* mm       = bases + 256;                         // 256
    u32* wstart   = mm + 256;                            // 257 (pad to 512)
    u32* pal_u32  = wstart + 512;                        // 4096 (u64-aligned)
    u32* records  = pal_u32 + 4096;                      // NPTS*KSTEPS
    u32* partials = records + (size_t)NPTS * KSTEPS;     // K5G*BKTPX*4
    const size_t need_u32 = (size_t)(partials - ws) + (size_t)K5G * BKTPX * 4;
    const size_t NEED = need_u32 * sizeof(u32);          // ~186 MB

    if (ws_size >= NEED) {
        k_count<<<dim3(NB), 256, 0, stream>>>(A, b, fcolor, xy0, c0, minv,
                                              rangev, fn_idx, skipk, counts);
        k_scanblocks<<<dim3(NBKT), 256, 0, stream>>>(counts, prefix, totals);
        k_meta<<<dim3(1), 256, 0, stream>>>(palette, totals, bases, mm, wstart,
                                            pal_u32);
        k_emit<<<dim3(NB), 256, 0, stream>>>(A, b, fcolor, xy0, c0, minv,
                                             rangev, fn_idx, skipk, prefix,
                                             bases, records);
        k_accum<<<dim3(K5G), 256, 0, stream>>>(pal_u32, totals, bases, mm,
                                               wstart, records, partials);
        k_final<<<dim3(HW / 256), 256, 0, stream>>>(partials, wstart,
                                                    raw_image, img);
    } else {
        const size_t need2 = (size_t)HW * 2 * sizeof(u64);
        hipMemsetAsync(d_ws, 0, need2, stream);
        flame_accum_packed<<<dim3(NB), 256, 0, stream>>>(
            palette, A, b, fcolor, xy0, c0, minv, rangev, fn_idx, skipk,
            (u64*)d_ws);
        reduce_packed<<<dim3((HW + 255) / 256), 256, 0, stream>>>(
            (const u64*)d_ws, raw_image, img);
    }
}

// Round 6
// 264.771 us; speedup vs baseline: 13.7263x; 1.0167x over previous
//
#include <hip/hip_runtime.h>

typedef unsigned int u32;
typedef unsigned long long u64;

#define NPTS   1000000
#define KSTEPS 32
#define NF     8
#define IMG_H  1024
#define IMG_W  1024
#define FID    1000
#define HW     (IMG_H * IMG_W)
#define NB     3907            // ceil(NPTS/256)
#define NBKT   256             // bucket = pixel >> 12  (4 image rows)
#define BKTPX  4096            // pixels per bucket
#define K5G    768             // accumulate workgroups (>= 256 + 508)
#define FPSCALE 4194304.0f     // 2^22 fixed point; capacity 1024 > max sum 488
#define FPINV   (1.0f / 4194304.0f)

// One chaos-game step, numpy-exact (no FMA contraction). Reads the packed
// table row s_tab[idx][8] = {a00,a01,a10,a11,b0,b1,fc,0} as two float4 LDS
// reads (2-way bank conflict = free) instead of 6 scalar reads.
#define FLAME_STEP(IDX, K)                                                     \
  {                                                                            \
    const float4 t0 = *(const float4*)&s_tab[(IDX) * 8];                       \
    const float4 t1 = *(const float4*)&s_tab[(IDX) * 8 + 4];                   \
    const float nx = __fadd_rn(__fadd_rn(__fmul_rn(t0.x,x),__fmul_rn(t0.y,y)),t1.x);\
    const float ny = __fadd_rn(__fadd_rn(__fmul_rn(t0.z,x),__fmul_rn(t0.w,y)),t1.y);\
    x = nx; y = ny;                                                            \
    c = __fmul_rn(__fadd_rn(c, t1.z), 0.5f);                                   \
    xb = (int)__fmul_rn(__fsub_rn(x, minx), rx);                               \
    yb = (int)__fmul_rn(__fsub_rn(y, miny), ry);                               \
    inb = (xb >= 0) & (xb < IMG_W) & (yb >= 0) & (yb < IMG_H) & ((K) >= skipk);\
  }

#define LOAD_TABLES()                                                          \
    if (threadIdx.x < NF) {                                                    \
        const int f = threadIdx.x;                                             \
        s_tab[f*8+0] = Amat[f*4+0]; s_tab[f*8+1] = Amat[f*4+1];                \
        s_tab[f*8+2] = Amat[f*4+2]; s_tab[f*8+3] = Amat[f*4+3];                \
        s_tab[f*8+4] = bvec[f*2+0]; s_tab[f*8+5] = bvec[f*2+1];                \
        s_tab[f*8+6] = fcolor[f];   s_tab[f*8+7] = 0.0f;                       \
    }

// Issue ALL 32 fn_idx loads (independent, affine addresses) before the chaos
// loop. sched_barrier(0) forbids the scheduler from sinking them to their
// uses — the wave then has 32 loads in flight and pays the ~600-cycle
// L2-miss latency once instead of 32 times on the serial k-chain.
#define PRELOAD_IDX()                                                          \
    int pidx[KSTEPS];                                                          \
    _Pragma("unroll")                                                          \
    for (int k = 0; k < KSTEPS; ++k) pidx[k] = fn_idx[(size_t)k * NPTS + i];   \
    __builtin_amdgcn_sched_barrier(0);

// ---------------------------------------------------------------------------
// K1a: per-(block,bucket) hit counts. counts[blk][bkt], no global atomics.
// ---------------------------------------------------------------------------
__global__ __launch_bounds__(256) void k_count(
    const float* __restrict__ Amat, const float* __restrict__ bvec,
    const float* __restrict__ fcolor,
    const float* __restrict__ xy0, const float* __restrict__ c0,
    const float* __restrict__ minv, const float* __restrict__ rangev,
    const int* __restrict__ fn_idx, const int* __restrict__ skipk_ptr,
    u32* __restrict__ counts)
{
    __shared__ u32 s_cnt[NBKT];
    __shared__ __align__(16) float s_tab[NF * 8];
    s_cnt[threadIdx.x] = 0u;
    LOAD_TABLES();
    __syncthreads();

    const int i = blockIdx.x * 256 + threadIdx.x;
    if (i < NPTS) {
        const int   skipk = skipk_ptr[0];
        const float minx = minv[0], miny = minv[1];
        const float rx = rangev[0], ry = rangev[1];
        const float2 xyv = ((const float2*)xy0)[i];
        float x = xyv.x, y = xyv.y, c = c0[i];
        PRELOAD_IDX();
        #pragma unroll
        for (int k = 0; k < KSTEPS; ++k) {
            const int idx = pidx[k];
            int xb, yb; bool inb;
            FLAME_STEP(idx, k);
            if (inb) atomicAdd(&s_cnt[xb >> 2], 1u);
        }
    }
    __syncthreads();
    counts[(size_t)blockIdx.x * NBKT + threadIdx.x] = s_cnt[threadIdx.x];
}

// ---------------------------------------------------------------------------
// K2a: per-bucket exclusive prefix over blocks; totals per bucket.
// ---------------------------------------------------------------------------
__global__ __launch_bounds__(256) void k_scanblocks(
    const u32* __restrict__ counts, u32* __restrict__ prefix,
    u32* __restrict__ totals)
{
    const int b = blockIdx.x, tid = threadIdx.x;
    u32 v[16]; u32 s = 0;
    #pragma unroll
    for (int j = 0; j < 16; ++j) {
        const int row = tid * 16 + j;
        v[j] = (row < NB) ? counts[(size_t)row * NBKT + b] : 0u;
        s += v[j];
    }
    __shared__ u32 sc[256];
    sc[tid] = s; __syncthreads();
    #pragma unroll
    for (int o = 1; o < 256; o <<= 1) {
        u32 t = (tid >= o) ? sc[tid - o] : 0u;
        __syncthreads();
        sc[tid] += t;
        __syncthreads();
    }
    u32 run = sc[tid] - s;   // exclusive
    #pragma unroll
    for (int j = 0; j < 16; ++j) {
        const int row = tid * 16 + j;
        if (row < NB) prefix[(size_t)row * NBKT + b] = run;
        run += v[j];
    }
    if (tid == 255) totals[b] = sc[255];
}

// ---------------------------------------------------------------------------
// K2b: bucket bases, chunk counts m[b], wstart scan, fixed-point palette.
// ---------------------------------------------------------------------------
__global__ __launch_bounds__(256) void k_meta(
    const float* __restrict__ palette,
    const u32* __restrict__ totals,
    u32* __restrict__ bases, u32* __restrict__ mm, u32* __restrict__ wstart,
    u32* __restrict__ pal_u32)
{
    __shared__ u32 sc[256];
    const int tid = threadIdx.x;

    for (int t = tid; t < FID * 4; t += 256)
        pal_u32[t] = __float2uint_rn(__fmul_rn(palette[t], FPSCALE));

    const u32 t0 = totals[tid];
    sc[tid] = t0; __syncthreads();
    #pragma unroll
    for (int o = 1; o < 256; o <<= 1) {
        u32 v = (tid >= o) ? sc[tid - o] : 0u;
        __syncthreads(); sc[tid] += v; __syncthreads();
    }
    const u32 total = sc[255];
    bases[tid] = sc[tid] - t0;

    const u32 m = 1u + (total ? (u32)((508ull * t0) / total) : 0u);
    mm[tid] = m;
    __syncthreads(); sc[tid] = m; __syncthreads();
    #pragma unroll
    for (int o = 1; o < 256; o <<= 1) {
        u32 v = (tid >= o) ? sc[tid - o] : 0u;
        __syncthreads(); sc[tid] += v; __syncthreads();
    }
    wstart[tid] = sc[tid] - m;
    if (tid == 255) wstart[256] = sc[255];
}

// ---------------------------------------------------------------------------
// K1b: re-iterate, emit records (pixel<<10 | pal) into bucketed regions.
// ---------------------------------------------------------------------------
__global__ __launch_bounds__(256) void k_emit(
    const float* __restrict__ Amat, const float* __restrict__ bvec,
    const float* __restrict__ fcolor,
    const float* __restrict__ xy0, const float* __restrict__ c0,
    const float* __restrict__ minv, const float* __restrict__ rangev,
    const int* __restrict__ fn_idx, const int* __restrict__ skipk_ptr,
    const u32* __restrict__ prefix, const u32* __restrict__ bases,
    u32* __restrict__ records)
{
    __shared__ u32 s_cur[NBKT];
    __shared__ __align__(16) float s_tab[NF * 8];
    s_cur[threadIdx.x] = bases[threadIdx.x] +
                         prefix[(size_t)blockIdx.x * NBKT + threadIdx.x];
    LOAD_TABLES();
    __syncthreads();

    const int i = blockIdx.x * 256 + threadIdx.x;
    if (i < NPTS) {
        const int   skipk = skipk_ptr[0];
        const float minx = minv[0], miny = minv[1];
        const float rx = rangev[0], ry = rangev[1];
        const float2 xyv = ((const float2*)xy0)[i];
        float x = xyv.x, y = xyv.y, c = c0[i];
        PRELOAD_IDX();
        #pragma unroll
        for (int k = 0; k < KSTEPS; ++k) {
            const int idx = pidx[k];
            int xb, yb; bool inb;
            FLAME_STEP(idx, k);
            if (inb) {
                int pi = (int)__fadd_rn(__fmul_rn(c, 999.0f), 0.0005f);
                pi = min(max(pi, 0), FID - 1);
                const u32 r = (((u32)(xb << 10 | yb)) << 10) | (u32)pi;
                const u32 pos = atomicAdd(&s_cur[r >> 22], 1u);
                records[pos] = r;
            }
        }
    }
}

// ---------------------------------------------------------------------------
// K5: per-chunk LDS tile accumulation. Channels packed 2-per-u64 ds_add:
// 2 LDS atomics per record instead of 4 (2^22 fixed point, capacity 1024).
// ---------------------------------------------------------------------------
__global__ __launch_bounds__(256) void k_accum(
    const u32* __restrict__ pal_u32,
    const u32* __restrict__ totals, const u32* __restrict__ bases,
    const u32* __restrict__ mm, const u32* __restrict__ wstart,
    const u32* __restrict__ records,
    u32* __restrict__ partials)
{
    __shared__ u64 tile[BKTPX * 2];     // 64 KB
    __shared__ u32 s_ws[NBKT + 1];
    const int tid = threadIdx.x, w = blockIdx.x;

    s_ws[tid] = wstart[tid];
    if (tid == 0) s_ws[NBKT] = wstart[NBKT];
    __syncthreads();
    if ((u32)w >= s_ws[NBKT]) return;   // uniform per block

    // largest b with wstart[b] <= w
    int b = 0;
    #pragma unroll
    for (int step = 128; step; step >>= 1)
        if (b + step <= 255 && s_ws[b + step] <= (u32)w) b += step;

    for (int t = tid; t < BKTPX * 2; t += 256) tile[t] = 0ull;
    __syncthreads();

    const u32 cnt = totals[b], m = mm[b], cch = (u32)w - s_ws[b];
    const u32 rs = bases[b] + (u32)(((u64)cnt * cch) / m);
    const u32 re = bases[b] + (u32)(((u64)cnt * (cch + 1)) / m);

    const u64* pal_u64 = (const u64*)pal_u32;
    for (u32 j = rs + tid; j < re; j += 256) {
        const u32 r = records[j];
        const u32 local = (r >> 10) & 4095u;
        const u32 pal = r & 1023u;
        const u64 w0 = pal_u64[pal * 2 + 0];
        const u64 w1 = pal_u64[pal * 2 + 1];
        atomicAdd(&tile[local * 2 + 0], w0);
        atomicAdd(&tile[local * 2 + 1], w1);
    }
    __syncthreads();

    uint4* dst = (uint4*)(partials + (size_t)w * BKTPX * 4);
    const uint4* src = (const uint4*)tile;
    for (int t = tid; t < BKTPX; t += 256) dst[t] = src[t];
}

// ---------------------------------------------------------------------------
// K6: sum partial tiles per bucket, unpack, add raw_image, write CHW out.
// ---------------------------------------------------------------------------
__global__ __launch_bounds__(256) void k_final(
    const u32* __restrict__ partials, const u32* __restrict__ wstart,
    const float* __restrict__ raw, float* __restrict__ out)
{
    const int p = blockIdx.x * 256 + threadIdx.x;
    const int b = p >> 12, local = p & 4095;
    u32 a0 = 0, a1 = 0, a2 = 0, a3 = 0;
    const u32 w0 = wstart[b], w1 = wstart[b + 1];
    for (u32 w = w0; w < w1; ++w) {
        const uint4 v = ((const uint4*)partials)[(size_t)w * BKTPX + local];
        a0 += v.x; a1 += v.y; a2 += v.z; a3 += v.w;
    }
    out[0*(size_t)HW + p] = __fadd_rn(raw[0*(size_t)HW + p], __fmul_rn((float)a0, FPINV));
    out[1*(size_t)HW + p] = __fadd_rn(raw[1*(size_t)HW + p], __fmul_rn((float)a1, FPINV));
    out[2*(size_t)HW + p] = __fadd_rn(raw[2*(size_t)HW + p], __fmul_rn((float)a2, FPINV));
    out[3*(size_t)HW + p] = __fadd_rn(raw[3*(size_t)HW + p], __fmul_rn((float)a3, FPINV));
}

// ---------------------------------------------------------------------------
// Fallback (round-3 path): packed u64 global atomics.
// ---------------------------------------------------------------------------
__global__ __launch_bounds__(256) void flame_accum_packed(
    const float* __restrict__ palette,
    const float* __restrict__ Amat, const float* __restrict__ bvec,
    const float* __restrict__ fcolor,
    const float* __restrict__ xy0, const float* __restrict__ c0,
    const float* __restrict__ minv, const float* __restrict__ rangev,
    const int* __restrict__ fn_idx, const int* __restrict__ skipk_ptr,
    u64* __restrict__ ws)
{
    __shared__ __align__(16) float s_pal[FID * 4];
    __shared__ __align__(16) float s_tab[NF * 8];
    for (int t = threadIdx.x; t < FID; t += 256)
        ((float4*)s_pal)[t] = ((const float4*)palette)[t];
    LOAD_TABLES();
    __syncthreads();

    const int i = blockIdx.x * 256 + threadIdx.x;
    if (i >= NPTS) return;
    const int   skipk = skipk_ptr[0];
    const float minx = minv[0], miny = minv[1];
    const float rx = rangev[0], ry = rangev[1];
    const float2 xyv = ((const float2*)xy0)[i];
    float x = xyv.x, y = xyv.y, c = c0[i];
    PRELOAD_IDX();
    #pragma unroll
    for (int k = 0; k < KSTEPS; ++k) {
        const int idx = pidx[k];
        int xb, yb; bool inb;
        FLAME_STEP(idx, k);
        if (inb) {
            int pi = (int)__fadd_rn(__fmul_rn(c, 999.0f), 0.0005f);
            pi = min(max(pi, 0), FID - 1);
            const float4 col = *(const float4*)&s_pal[pi * 4];
            const u32 u0 = __float2uint_rn(__fmul_rn(col.x, FPSCALE));
            const u32 u1 = __float2uint_rn(__fmul_rn(col.y, FPSCALE));
            const u32 u2 = __float2uint_rn(__fmul_rn(col.z, FPSCALE));
            const u32 u3 = __float2uint_rn(__fmul_rn(col.w, FPSCALE));
            u64* p = ws + ((size_t)xb * IMG_W + yb) * 2;
            atomicAdd(p + 0, (u64)u0 | ((u64)u1 << 32));
            atomicAdd(p + 1, (u64)u2 | ((u64)u3 << 32));
        }
    }
}

__global__ __launch_bounds__(256) void reduce_packed(
    const u64* __restrict__ ws, const float* __restrict__ raw_image,
    float* __restrict__ out)
{
    const int p = blockIdx.x * 256 + threadIdx.x;
    if (p >= HW) return;
    const u64 w0 = ws[(size_t)p * 2 + 0];
    const u64 w1 = ws[(size_t)p * 2 + 1];
    out[0*(size_t)HW+p] = raw_image[0*(size_t)HW+p] + (float)(u32)(w0 & 0xffffffffull) * FPINV;
    out[1*(size_t)HW+p] = raw_image[1*(size_t)HW+p] + (float)(u32)(w0 >> 32)           * FPINV;
    out[2*(size_t)HW+p] = raw_image[2*(size_t)HW+p] + (float)(u32)(w1 & 0xffffffffull) * FPINV;
    out[3*(size_t)HW+p] = raw_image[3*(size_t)HW+p] + (float)(u32)(w1 >> 32)           * FPINV;
}

extern "C" void kernel_launch(void* const* d_in, const int* in_sizes, int n_in,
                              void* d_out, int out_size, void* d_ws, size_t ws_size,
                              hipStream_t stream) {
    const float* raw_image = (const float*)d_in[0];
    const float* palette   = (const float*)d_in[1];
    const float* A         = (const float*)d_in[2];
    const float* b         = (const float*)d_in[3];
    const float* fcolor    = (const float*)d_in[4];
    const float* xy0       = (const float*)d_in[5];
    const float* c0        = (const float*)d_in[6];
    const float* minv      = (const float*)d_in[7];
    const float* rangev    = (const float*)d_in[8];
    const int*   fn_idx    = (const int*)d_in[9];
    const int*   skipk     = (const int*)d_in[10];
    float* img = (float*)d_out;

    // ws layout (u32 units)
    u32* ws = (u32*)d_ws;
    u32* counts   = ws;                                  // NB*256
    u32* prefix   = counts + (size_t)NB * NBKT;          // NB*256
    u32* totals   = prefix + (size_t)NB * NBKT;          // 256
    u32* bases    = totals + 256;                        // 256
    u32* mm       = bases + 256;                         // 256
    u32* wstart   = mm + 256;                            // 257 (pad to 512)
    u32* pal_u32  = wstart + 512;                        // 4096 (u64-aligned)
    u32* records  = pal_u32 + 4096;                      // NPTS*KSTEPS
    u32* partials = records + (size_t)NPTS * KSTEPS;     // K5G*BKTPX*4
    const size_t need_u32 = (size_t)(partials - ws) + (size_t)K5G * BKTPX * 4;
    const size_t NEED = need_u32 * sizeof(u32);          // ~186 MB

    if (ws_size >= NEED) {
        k_count<<<dim3(NB), 256, 0, stream>>>(A, b, fcolor, xy0, c0, minv,
                                              rangev, fn_idx, skipk, counts);
        k_scanblocks<<<dim3(NBKT), 256, 0, stream>>>(counts, prefix, totals);
        k_meta<<<dim3(1), 256, 0, stream>>>(palette, totals, bases, mm, wstart,
                                            pal_u32);
        k_emit<<<dim3(NB), 256, 0, stream>>>(A, b, fcolor, xy0, c0, minv,
                                             rangev, fn_idx, skipk, prefix,
                                             bases, records);
        k_accum<<<dim3(K5G), 256, 0, stream>>>(pal_u32, totals, bases, mm,
                                               wstart, records, partials);
        k_final<<<dim3(HW / 256), 256, 0, stream>>>(partials, wstart,
                                                    raw_image, img);
    } else {
        const size_t need2 = (size_t)HW * 2 * sizeof(u64);
        hipMemsetAsync(d_ws, 0, need2, stream);
        flame_accum_packed<<<dim3(NB), 256, 0, stream>>>(
            palette, A, b, fcolor, xy0, c0, minv, rangev, fn_idx, skipk,
            (u64*)d_ws);
        reduce_packed<<<dim3((HW + 255) / 256), 256, 0, stream>>>(
            (const u64*)d_ws, raw_image, img);
    }
}

// Round 7
// 255.691 us; speedup vs baseline: 14.2137x; 1.0355x over previous
//
#include <hip/hip_runtime.h>

typedef unsigned int u32;
typedef unsigned long long u64;

#define NPTS   1000000
#define KSTEPS 32
#define NF     8
#define IMG_H  1024
#define IMG_W  1024
#define FID    1000
#define HW     (IMG_H * IMG_W)
#define NB     3907            // ceil(NPTS/256)
#define NBKT   256             // bucket = pixel >> 12  (4 image rows)
#define BKTPX  4096            // pixels per bucket
#define K5G    768             // accumulate workgroups (>= 256 + 508)
#define FPSCALE 4194304.0f     // 2^22 fixed point; capacity 1024 > max sum 488
#define FPINV   (1.0f / 4194304.0f)

// Extract step K's function index from packed nibble words p0..p3 (K is a
// compile-time constant after full unroll -> single shift+and).
#define GETIDX(K)                                                              \
    ((int)(((((K) >> 3) == 0 ? p0 : ((K) >> 3) == 1 ? p1                       \
            : ((K) >> 3) == 2 ? p2 : p3) >> (((K) & 7) * 4)) & 7u))

// One chaos-game step, numpy-exact (no FMA contraction). Scalar LDS table
// reads: 8 distinct addresses max -> broadcast within same-idx lanes,
// 2-way bank aliasing across idx (free on CDNA4).
#define FLAME_STEP(IDX, K)                                                     \
  {                                                                            \
    const float a00 = s_tab[(IDX)*8+0], a01 = s_tab[(IDX)*8+1];                \
    const float a10 = s_tab[(IDX)*8+2], a11 = s_tab[(IDX)*8+3];                \
    const float b0  = s_tab[(IDX)*8+4], b1  = s_tab[(IDX)*8+5];                \
    const float fc  = s_tab[(IDX)*8+6];                                        \
    const float nx = __fadd_rn(__fadd_rn(__fmul_rn(a00,x),__fmul_rn(a01,y)),b0);\
    const float ny = __fadd_rn(__fadd_rn(__fmul_rn(a10,x),__fmul_rn(a11,y)),b1);\
    x = nx; y = ny;                                                            \
    c = __fmul_rn(__fadd_rn(c, fc), 0.5f);                                     \
    xb = (int)__fmul_rn(__fsub_rn(x, minx), rx);                               \
    yb = (int)__fmul_rn(__fsub_rn(y, miny), ry);                               \
    inb = (xb >= 0) & (xb < IMG_W) & (yb >= 0) & (yb < IMG_H) & ((K) >= skipk);\
  }

#define LOAD_TABLES()                                                          \
    if (threadIdx.x < NF) {                                                    \
        const int f = threadIdx.x;                                             \
        s_tab[f*8+0] = Amat[f*4+0]; s_tab[f*8+1] = Amat[f*4+1];                \
        s_tab[f*8+2] = Amat[f*4+2]; s_tab[f*8+3] = Amat[f*4+3];                \
        s_tab[f*8+4] = bvec[f*2+0]; s_tab[f*8+5] = bvec[f*2+1];                \
        s_tab[f*8+6] = fcolor[f];   s_tab[f*8+7] = 0.0f;                       \
    }

// ---------------------------------------------------------------------------
// K1: pack fn_idx nibbles (32 INDEPENDENT coalesced loads -> HW pipelines
// them; no serial chain) + run flame + per-(block,bucket) hit counts.
// ---------------------------------------------------------------------------
__global__ __launch_bounds__(256) void k_pack_count(
    const float* __restrict__ Amat, const float* __restrict__ bvec,
    const float* __restrict__ fcolor,
    const float* __restrict__ xy0, const float* __restrict__ c0,
    const float* __restrict__ minv, const float* __restrict__ rangev,
    const int* __restrict__ fn_idx, const int* __restrict__ skipk_ptr,
    u32* __restrict__ packed, u32* __restrict__ counts)
{
    __shared__ u32 s_cnt[NBKT];
    __shared__ float s_tab[NF * 8];
    s_cnt[threadIdx.x] = 0u;
    LOAD_TABLES();
    __syncthreads();

    const int i = blockIdx.x * 256 + threadIdx.x;
    if (i < NPTS) {
        u32 p0 = 0, p1 = 0, p2 = 0, p3 = 0;
        #pragma unroll
        for (int k = 0; k < 8; ++k)
            p0 |= ((u32)fn_idx[(size_t)k * NPTS + i] & 7u) << (k * 4);
        #pragma unroll
        for (int k = 0; k < 8; ++k)
            p1 |= ((u32)fn_idx[(size_t)(k + 8) * NPTS + i] & 7u) << (k * 4);
        #pragma unroll
        for (int k = 0; k < 8; ++k)
            p2 |= ((u32)fn_idx[(size_t)(k + 16) * NPTS + i] & 7u) << (k * 4);
        #pragma unroll
        for (int k = 0; k < 8; ++k)
            p3 |= ((u32)fn_idx[(size_t)(k + 24) * NPTS + i] & 7u) << (k * 4);

        ((uint4*)packed)[i] = make_uint4(p0, p1, p2, p3);

        const int   skipk = skipk_ptr[0];
        const float minx = minv[0], miny = minv[1];
        const float rx = rangev[0], ry = rangev[1];
        const float2 xyv = ((const float2*)xy0)[i];
        float x = xyv.x, y = xyv.y, c = c0[i];
        #pragma unroll
        for (int k = 0; k < KSTEPS; ++k) {
            const int idx = GETIDX(k);
            int xb, yb; bool inb;
            FLAME_STEP(idx, k);
            if (inb) atomicAdd(&s_cnt[xb >> 2], 1u);
        }
    }
    __syncthreads();
    counts[(size_t)blockIdx.x * NBKT + threadIdx.x] = s_cnt[threadIdx.x];
}

// ---------------------------------------------------------------------------
// K2a: per-bucket exclusive prefix over blocks; totals per bucket.
// ---------------------------------------------------------------------------
__global__ __launch_bounds__(256) void k_scanblocks(
    const u32* __restrict__ counts, u32* __restrict__ prefix,
    u32* __restrict__ totals)
{
    const int b = blockIdx.x, tid = threadIdx.x;
    u32 v[16]; u32 s = 0;
    #pragma unroll
    for (int j = 0; j < 16; ++j) {
        const int row = tid * 16 + j;
        v[j] = (row < NB) ? counts[(size_t)row * NBKT + b] : 0u;
        s += v[j];
    }
    __shared__ u32 sc[256];
    sc[tid] = s; __syncthreads();
    #pragma unroll
    for (int o = 1; o < 256; o <<= 1) {
        u32 t = (tid >= o) ? sc[tid - o] : 0u;
        __syncthreads();
        sc[tid] += t;
        __syncthreads();
    }
    u32 run = sc[tid] - s;   // exclusive
    #pragma unroll
    for (int j = 0; j < 16; ++j) {
        const int row = tid * 16 + j;
        if (row < NB) prefix[(size_t)row * NBKT + b] = run;
        run += v[j];
    }
    if (tid == 255) totals[b] = sc[255];
}

// ---------------------------------------------------------------------------
// K2b: bucket bases, chunk counts m[b], wstart scan, fixed-point palette.
// ---------------------------------------------------------------------------
__global__ __launch_bounds__(256) void k_meta(
    const float* __restrict__ palette,
    const u32* __restrict__ totals,
    u32* __restrict__ bases, u32* __restrict__ mm, u32* __restrict__ wstart,
    u32* __restrict__ pal_u32)
{
    __shared__ u32 sc[256];
    const int tid = threadIdx.x;

    for (int t = tid; t < FID * 4; t += 256)
        pal_u32[t] = __float2uint_rn(__fmul_rn(palette[t], FPSCALE));

    const u32 t0 = totals[tid];
    sc[tid] = t0; __syncthreads();
    #pragma unroll
    for (int o = 1; o < 256; o <<= 1) {
        u32 v = (tid >= o) ? sc[tid - o] : 0u;
        __syncthreads(); sc[tid] += v; __syncthreads();
    }
    const u32 total = sc[255];
    bases[tid] = sc[tid] - t0;

    const u32 m = 1u + (total ? (u32)((508ull * t0) / total) : 0u);
    mm[tid] = m;
    __syncthreads(); sc[tid] = m; __syncthreads();
    #pragma unroll
    for (int o = 1; o < 256; o <<= 1) {
        u32 v = (tid >= o) ? sc[tid - o] : 0u;
        __syncthreads(); sc[tid] += v; __syncthreads();
    }
    wstart[tid] = sc[tid] - m;
    if (tid == 255) wstart[256] = sc[255];
}

// ---------------------------------------------------------------------------
// K3: re-run flame from PACKED indices (one uint4 load per point), emit
// records (pixel<<10 | pal) into bucketed regions via LDS cursors.
// ---------------------------------------------------------------------------
__global__ __launch_bounds__(256) void k_emit(
    const float* __restrict__ Amat, const float* __restrict__ bvec,
    const float* __restrict__ fcolor,
    const float* __restrict__ xy0, const float* __restrict__ c0,
    const float* __restrict__ minv, const float* __restrict__ rangev,
    const u32* __restrict__ packed, const int* __restrict__ skipk_ptr,
    const u32* __restrict__ prefix, const u32* __restrict__ bases,
    u32* __restrict__ records)
{
    __shared__ u32 s_cur[NBKT];
    __shared__ float s_tab[NF * 8];
    s_cur[threadIdx.x] = bases[threadIdx.x] +
                         prefix[(size_t)blockIdx.x * NBKT + threadIdx.x];
    LOAD_TABLES();
    __syncthreads();

    const int i = blockIdx.x * 256 + threadIdx.x;
    if (i < NPTS) {
        const uint4 pw = ((const uint4*)packed)[i];
        const u32 p0 = pw.x, p1 = pw.y, p2 = pw.z, p3 = pw.w;
        const int   skipk = skipk_ptr[0];
        const float minx = minv[0], miny = minv[1];
        const float rx = rangev[0], ry = rangev[1];
        const float2 xyv = ((const float2*)xy0)[i];
        float x = xyv.x, y = xyv.y, c = c0[i];
        #pragma unroll
        for (int k = 0; k < KSTEPS; ++k) {
            const int idx = GETIDX(k);
            int xb, yb; bool inb;
            FLAME_STEP(idx, k);
            if (inb) {
                int pi = (int)__fadd_rn(__fmul_rn(c, 999.0f), 0.0005f);
                pi = min(max(pi, 0), FID - 1);
                const u32 r = (((u32)(xb << 10 | yb)) << 10) | (u32)pi;
                const u32 pos = atomicAdd(&s_cur[r >> 22], 1u);
                records[pos] = r;
            }
        }
    }
}

// ---------------------------------------------------------------------------
// K4: per-chunk LDS tile accumulation. Channels packed 2-per-u64 ds_add.
// ---------------------------------------------------------------------------
__global__ __launch_bounds__(256) void k_accum(
    const u32* __restrict__ pal_u32,
    const u32* __restrict__ totals, const u32* __restrict__ bases,
    const u32* __restrict__ mm, const u32* __restrict__ wstart,
    const u32* __restrict__ records,
    u32* __restrict__ partials)
{
    __shared__ u64 tile[BKTPX * 2];     // 64 KB
    __shared__ u32 s_ws[NBKT + 1];
    const int tid = threadIdx.x, w = blockIdx.x;

    s_ws[tid] = wstart[tid];
    if (tid == 0) s_ws[NBKT] = wstart[NBKT];
    __syncthreads();
    if ((u32)w >= s_ws[NBKT]) return;   // uniform per block

    // largest b with wstart[b] <= w
    int b = 0;
    #pragma unroll
    for (int step = 128; step; step >>= 1)
        if (b + step <= 255 && s_ws[b + step] <= (u32)w) b += step;

    for (int t = tid; t < BKTPX * 2; t += 256) tile[t] = 0ull;
    __syncthreads();

    const u32 cnt = totals[b], m = mm[b], cch = (u32)w - s_ws[b];
    const u32 rs = bases[b] + (u32)(((u64)cnt * cch) / m);
    const u32 re = bases[b] + (u32)(((u64)cnt * (cch + 1)) / m);

    const u64* pal_u64 = (const u64*)pal_u32;
    for (u32 j = rs + tid; j < re; j += 256) {
        const u32 r = records[j];
        const u32 local = (r >> 10) & 4095u;
        const u32 pal = r & 1023u;
        const u64 w0 = pal_u64[pal * 2 + 0];
        const u64 w1 = pal_u64[pal * 2 + 1];
        atomicAdd(&tile[local * 2 + 0], w0);
        atomicAdd(&tile[local * 2 + 1], w1);
    }
    __syncthreads();

    uint4* dst = (uint4*)(partials + (size_t)w * BKTPX * 4);
    const uint4* src = (const uint4*)tile;
    for (int t = tid; t < BKTPX; t += 256) dst[t] = src[t];
}

// ---------------------------------------------------------------------------
// K5: sum partial tiles per bucket, unpack, add raw_image, write CHW out.
// ---------------------------------------------------------------------------
__global__ __launch_bounds__(256) void k_final(
    const u32* __restrict__ partials, const u32* __restrict__ wstart,
    const float* __restrict__ raw, float* __restrict__ out)
{
    const int p = blockIdx.x * 256 + threadIdx.x;
    const int b = p >> 12, local = p & 4095;
    u32 a0 = 0, a1 = 0, a2 = 0, a3 = 0;
    const u32 w0 = wstart[b], w1 = wstart[b + 1];
    for (u32 w = w0; w < w1; ++w) {
        const uint4 v = ((const uint4*)partials)[(size_t)w * BKTPX + local];
        a0 += v.x; a1 += v.y; a2 += v.z; a3 += v.w;
    }
    out[0*(size_t)HW + p] = __fadd_rn(raw[0*(size_t)HW + p], __fmul_rn((float)a0, FPINV));
    out[1*(size_t)HW + p] = __fadd_rn(raw[1*(size_t)HW + p], __fmul_rn((float)a1, FPINV));
    out[2*(size_t)HW + p] = __fadd_rn(raw[2*(size_t)HW + p], __fmul_rn((float)a2, FPINV));
    out[3*(size_t)HW + p] = __fadd_rn(raw[3*(size_t)HW + p], __fmul_rn((float)a3, FPINV));
}

// ---------------------------------------------------------------------------
// Fallback (ws too small): packed u64 global atomics (round-3 path).
// ---------------------------------------------------------------------------
__global__ __launch_bounds__(256) void flame_accum_packed(
    const float* __restrict__ palette,
    const float* __restrict__ Amat, const float* __restrict__ bvec,
    const float* __restrict__ fcolor,
    const float* __restrict__ xy0, const float* __restrict__ c0,
    const float* __restrict__ minv, const float* __restrict__ rangev,
    const int* __restrict__ fn_idx, const int* __restrict__ skipk_ptr,
    u64* __restrict__ ws)
{
    __shared__ __align__(16) float s_pal[FID * 4];
    __shared__ float s_tab[NF * 8];
    for (int t = threadIdx.x; t < FID; t += 256)
        ((float4*)s_pal)[t] = ((const float4*)palette)[t];
    LOAD_TABLES();
    __syncthreads();

    const int i = blockIdx.x * 256 + threadIdx.x;
    if (i >= NPTS) return;
    const int   skipk = skipk_ptr[0];
    const float minx = minv[0], miny = minv[1];
    const float rx = rangev[0], ry = rangev[1];
    const float2 xyv = ((const float2*)xy0)[i];
    float x = xyv.x, y = xyv.y, c = c0[i];
    for (int k = 0; k < KSTEPS; ++k) {
        const int idx = fn_idx[(size_t)k * NPTS + i];
        int xb, yb; bool inb;
        FLAME_STEP(idx, k);
        if (inb) {
            int pi = (int)__fadd_rn(__fmul_rn(c, 999.0f), 0.0005f);
            pi = min(max(pi, 0), FID - 1);
            const float4 col = *(const float4*)&s_pal[pi * 4];
            const u32 u0 = __float2uint_rn(__fmul_rn(col.x, FPSCALE));
            const u32 u1 = __float2uint_rn(__fmul_rn(col.y, FPSCALE));
            const u32 u2 = __float2uint_rn(__fmul_rn(col.z, FPSCALE));
            const u32 u3 = __float2uint_rn(__fmul_rn(col.w, FPSCALE));
            u64* p = ws + ((size_t)xb * IMG_W + yb) * 2;
            atomicAdd(p + 0, (u64)u0 | ((u64)u1 << 32));
            atomicAdd(p + 1, (u64)u2 | ((u64)u3 << 32));
        }
    }
}

__global__ __launch_bounds__(256) void reduce_packed(
    const u64* __restrict__ ws, const float* __restrict__ raw_image,
    float* __restrict__ out)
{
    const int p = blockIdx.x * 256 + threadIdx.x;
    if (p >= HW) return;
    const u64 w0 = ws[(size_t)p * 2 + 0];
    const u64 w1 = ws[(size_t)p * 2 + 1];
    out[0*(size_t)HW+p] = raw_image[0*(size_t)HW+p] + (float)(u32)(w0 & 0xffffffffull) * FPINV;
    out[1*(size_t)HW+p] = raw_image[1*(size_t)HW+p] + (float)(u32)(w0 >> 32)           * FPINV;
    out[2*(size_t)HW+p] = raw_image[2*(size_t)HW+p] + (float)(u32)(w1 & 0xffffffffull) * FPINV;
    out[3*(size_t)HW+p] = raw_image[3*(size_t)HW+p] + (float)(u32)(w1 >> 32)           * FPINV;
}

extern "C" void kernel_launch(void* const* d_in, const int* in_sizes, int n_in,
                              void* d_out, int out_size, void* d_ws, size_t ws_size,
                              hipStream_t stream) {
    const float* raw_image = (const float*)d_in[0];
    const float* palette   = (const float*)d_in[1];
    const float* A         = (const float*)d_in[2];
    const float* b         = (const float*)d_in[3];
    const float* fcolor    = (const float*)d_in[4];
    const float* xy0       = (const float*)d_in[5];
    const float* c0        = (const float*)d_in[6];
    const float* minv      = (const float*)d_in[7];
    const float* rangev    = (const float*)d_in[8];
    const int*   fn_idx    = (const int*)d_in[9];
    const int*   skipk     = (const int*)d_in[10];
    float* img = (float*)d_out;

    // ws layout (u32 units)
    u32* ws = (u32*)d_ws;
    u32* counts   = ws;                                  // NB*256
    u32* prefix   = counts + (size_t)NB * NBKT;          // NB*256
    u32* totals   = prefix + (size_t)NB * NBKT;          // 256
    u32* bases    = totals + 256;                        // 256
    u32* mm       = bases + 256;                         // 256
    u32* wstart   = mm + 256;                            // 257 (pad to 512)
    u32* pal_u32  = wstart + 512;                        // 4096 (u64-aligned)
    u32* records  = pal_u32 + 4096;                      // NPTS*KSTEPS
    u32* partials = records + (size_t)NPTS * KSTEPS;     // K5G*BKTPX*4
    // packed fn_idx nibbles (16 MB) alias the FRONT of partials: packed is
    // dead once k_emit finishes; partials are written only in k_accum,
    // which is stream-ordered after k_emit.
    u32* packed   = partials;                            // NPTS*4 (aliased)
    const size_t need_u32 = (size_t)(partials - ws) + (size_t)K5G * BKTPX * 4;
    const size_t NEED = need_u32 * sizeof(u32);          // ~186 MB

    if (ws_size >= NEED) {
        k_pack_count<<<dim3(NB), 256, 0, stream>>>(A, b, fcolor, xy0, c0,
                                                   minv, rangev, fn_idx, skipk,
                                                   packed, counts);
        k_scanblocks<<<dim3(NBKT), 256, 0, stream>>>(counts, prefix, totals);
        k_meta<<<dim3(1), 256, 0, stream>>>(palette, totals, bases, mm, wstart,
                                            pal_u32);
        k_emit<<<dim3(NB), 256, 0, stream>>>(A, b, fcolor, xy0, c0, minv,
                                             rangev, packed, skipk, prefix,
                                             bases, records);
        k_accum<<<dim3(K5G), 256, 0, stream>>>(pal_u32, totals, bases, mm,
                                               wstart, records, partials);
        k_final<<<dim3(HW / 256), 256, 0, stream>>>(partials, wstart,
                                                    raw_image, img);
    } else {
        const size_t need2 = (size_t)HW * 2 * sizeof(u64);
        hipMemsetAsync(d_ws, 0, need2, stream);
        flame_accum_packed<<<dim3(NB), 256, 0, stream>>>(
            palette, A, b, fcolor, xy0, c0, minv, rangev, fn_idx, skipk,
            (u64*)d_ws);
        reduce_packed<<<dim3((HW + 255) / 256), 256, 0, stream>>>(
            (const u64*)d_ws, raw_image, img);
    }
}

// Round 8
// 243.013 us; speedup vs baseline: 14.9553x; 1.0522x over previous
//
#include <hip/hip_runtime.h>

typedef unsigned int u32;
typedef unsigned long long u64;

#define NPTS   1000000
#define KSTEPS 32
#define NF     8
#define IMG_H  1024
#define IMG_W  1024
#define FID    1000
#define HW     (IMG_H * IMG_W)
#define NB     3907            // ceil(NPTS/256)
#define NBKT   512             // bucket = pixel >> 11  (2 image rows)
#define BKTPX  2048            // pixels per bucket
#define K5G    1024            // accumulate workgroups (>= 512 + 508)
#define FPSCALE 4194304.0f     // 2^22 fixed point; capacity 1024 > max sum 488
#define FPINV   (1.0f / 4194304.0f)

// Extract step K's function index from packed nibble words p0..p3 (K is a
// compile-time constant after full unroll -> single shift+and).
#define GETIDX(K)                                                              \
    ((int)(((((K) >> 3) == 0 ? p0 : ((K) >> 3) == 1 ? p1                       \
            : ((K) >> 3) == 2 ? p2 : p3) >> (((K) & 7) * 4)) & 7u))

// One chaos-game step, numpy-exact (no FMA contraction). Scalar LDS table
// reads: 8 distinct rows max -> broadcast/2-way aliasing (free on CDNA4).
#define FLAME_STEP(IDX, K)                                                     \
  {                                                                            \
    const float a00 = s_tab[(IDX)*8+0], a01 = s_tab[(IDX)*8+1];                \
    const float a10 = s_tab[(IDX)*8+2], a11 = s_tab[(IDX)*8+3];                \
    const float b0  = s_tab[(IDX)*8+4], b1  = s_tab[(IDX)*8+5];                \
    const float fc  = s_tab[(IDX)*8+6];                                        \
    const float nx = __fadd_rn(__fadd_rn(__fmul_rn(a00,x),__fmul_rn(a01,y)),b0);\
    const float ny = __fadd_rn(__fadd_rn(__fmul_rn(a10,x),__fmul_rn(a11,y)),b1);\
    x = nx; y = ny;                                                            \
    c = __fmul_rn(__fadd_rn(c, fc), 0.5f);                                     \
    xb = (int)__fmul_rn(__fsub_rn(x, minx), rx);                               \
    yb = (int)__fmul_rn(__fsub_rn(y, miny), ry);                               \
    inb = (xb >= 0) & (xb < IMG_W) & (yb >= 0) & (yb < IMG_H) & ((K) >= skipk);\
  }

#define LOAD_TABLES()                                                          \
    if (threadIdx.x < NF) {                                                    \
        const int f = threadIdx.x;                                             \
        s_tab[f*8+0] = Amat[f*4+0]; s_tab[f*8+1] = Amat[f*4+1];                \
        s_tab[f*8+2] = Amat[f*4+2]; s_tab[f*8+3] = Amat[f*4+3];                \
        s_tab[f*8+4] = bvec[f*2+0]; s_tab[f*8+5] = bvec[f*2+1];                \
        s_tab[f*8+6] = fcolor[f];   s_tab[f*8+7] = 0.0f;                       \
    }

// ---------------------------------------------------------------------------
// K1: pack fn_idx nibbles (32 INDEPENDENT coalesced loads -> HW pipelines
// them) + run flame + per-(block,bucket) hit counts.
// ---------------------------------------------------------------------------
__global__ __launch_bounds__(256) void k_pack_count(
    const float* __restrict__ Amat, const float* __restrict__ bvec,
    const float* __restrict__ fcolor,
    const float* __restrict__ xy0, const float* __restrict__ c0,
    const float* __restrict__ minv, const float* __restrict__ rangev,
    const int* __restrict__ fn_idx, const int* __restrict__ skipk_ptr,
    u32* __restrict__ packed, u32* __restrict__ counts)
{
    __shared__ u32 s_cnt[NBKT];
    __shared__ float s_tab[NF * 8];
    s_cnt[threadIdx.x] = 0u;
    s_cnt[threadIdx.x + 256] = 0u;
    LOAD_TABLES();
    __syncthreads();

    const int i = blockIdx.x * 256 + threadIdx.x;
    if (i < NPTS) {
        u32 p0 = 0, p1 = 0, p2 = 0, p3 = 0;
        #pragma unroll
        for (int k = 0; k < 8; ++k)
            p0 |= ((u32)fn_idx[(size_t)k * NPTS + i] & 7u) << (k * 4);
        #pragma unroll
        for (int k = 0; k < 8; ++k)
            p1 |= ((u32)fn_idx[(size_t)(k + 8) * NPTS + i] & 7u) << (k * 4);
        #pragma unroll
        for (int k = 0; k < 8; ++k)
            p2 |= ((u32)fn_idx[(size_t)(k + 16) * NPTS + i] & 7u) << (k * 4);
        #pragma unroll
        for (int k = 0; k < 8; ++k)
            p3 |= ((u32)fn_idx[(size_t)(k + 24) * NPTS + i] & 7u) << (k * 4);

        ((uint4*)packed)[i] = make_uint4(p0, p1, p2, p3);

        const int   skipk = skipk_ptr[0];
        const float minx = minv[0], miny = minv[1];
        const float rx = rangev[0], ry = rangev[1];
        const float2 xyv = ((const float2*)xy0)[i];
        float x = xyv.x, y = xyv.y, c = c0[i];
        #pragma unroll
        for (int k = 0; k < KSTEPS; ++k) {
            const int idx = GETIDX(k);
            int xb, yb; bool inb;
            FLAME_STEP(idx, k);
            if (inb) atomicAdd(&s_cnt[xb >> 1], 1u);   // bucket = pixel>>11 = xb>>1
        }
    }
    __syncthreads();
    counts[(size_t)blockIdx.x * NBKT + threadIdx.x] = s_cnt[threadIdx.x];
    counts[(size_t)blockIdx.x * NBKT + threadIdx.x + 256] = s_cnt[threadIdx.x + 256];
}

// ---------------------------------------------------------------------------
// K2a: per-bucket exclusive prefix over blocks; totals per bucket.
// grid = NBKT (one wg per bucket).
// ---------------------------------------------------------------------------
__global__ __launch_bounds__(256) void k_scanblocks(
    const u32* __restrict__ counts, u32* __restrict__ prefix,
    u32* __restrict__ totals)
{
    const int b = blockIdx.x, tid = threadIdx.x;
    u32 v[16]; u32 s = 0;
    #pragma unroll
    for (int j = 0; j < 16; ++j) {
        const int row = tid * 16 + j;
        v[j] = (row < NB) ? counts[(size_t)row * NBKT + b] : 0u;
        s += v[j];
    }
    __shared__ u32 sc[256];
    sc[tid] = s; __syncthreads();
    #pragma unroll
    for (int o = 1; o < 256; o <<= 1) {
        u32 t = (tid >= o) ? sc[tid - o] : 0u;
        __syncthreads();
        sc[tid] += t;
        __syncthreads();
    }
    u32 run = sc[tid] - s;   // exclusive
    #pragma unroll
    for (int j = 0; j < 16; ++j) {
        const int row = tid * 16 + j;
        if (row < NB) prefix[(size_t)row * NBKT + b] = run;
        run += v[j];
    }
    if (tid == 255) totals[b] = sc[255];
}

// ---------------------------------------------------------------------------
// K2b: bucket bases, chunk counts m[b], wstart scan, fixed-point palette.
// Single workgroup, 512 threads (one per bucket).
// ---------------------------------------------------------------------------
__global__ __launch_bounds__(512) void k_meta(
    const float* __restrict__ palette,
    const u32* __restrict__ totals,
    u32* __restrict__ bases, u32* __restrict__ mm, u32* __restrict__ wstart,
    u32* __restrict__ pal_u32)
{
    __shared__ u32 sc[NBKT];
    const int tid = threadIdx.x;

    for (int t = tid; t < FID * 4; t += 512)
        pal_u32[t] = __float2uint_rn(__fmul_rn(palette[t], FPSCALE));

    const u32 t0 = totals[tid];
    sc[tid] = t0; __syncthreads();
    #pragma unroll
    for (int o = 1; o < NBKT; o <<= 1) {
        u32 v = (tid >= o) ? sc[tid - o] : 0u;
        __syncthreads(); sc[tid] += v; __syncthreads();
    }
    const u32 total = sc[NBKT - 1];
    bases[tid] = sc[tid] - t0;

    const u32 m = 1u + (total ? (u32)((508ull * t0) / total) : 0u);
    mm[tid] = m;
    __syncthreads(); sc[tid] = m; __syncthreads();
    #pragma unroll
    for (int o = 1; o < NBKT; o <<= 1) {
        u32 v = (tid >= o) ? sc[tid - o] : 0u;
        __syncthreads(); sc[tid] += v; __syncthreads();
    }
    wstart[tid] = sc[tid] - m;
    if (tid == NBKT - 1) wstart[NBKT] = sc[NBKT - 1];
}

// ---------------------------------------------------------------------------
// K3: re-run flame from PACKED indices (one uint4 load per point), emit
// records (pixel<<10 | pal) into bucketed regions via LDS cursors.
// ---------------------------------------------------------------------------
__global__ __launch_bounds__(256) void k_emit(
    const float* __restrict__ Amat, const float* __restrict__ bvec,
    const float* __restrict__ fcolor,
    const float* __restrict__ xy0, const float* __restrict__ c0,
    const float* __restrict__ minv, const float* __restrict__ rangev,
    const u32* __restrict__ packed, const int* __restrict__ skipk_ptr,
    const u32* __restrict__ prefix, const u32* __restrict__ bases,
    u32* __restrict__ records)
{
    __shared__ u32 s_cur[NBKT];
    __shared__ float s_tab[NF * 8];
    s_cur[threadIdx.x] = bases[threadIdx.x] +
                         prefix[(size_t)blockIdx.x * NBKT + threadIdx.x];
    s_cur[threadIdx.x + 256] = bases[threadIdx.x + 256] +
                         prefix[(size_t)blockIdx.x * NBKT + threadIdx.x + 256];
    LOAD_TABLES();
    __syncthreads();

    const int i = blockIdx.x * 256 + threadIdx.x;
    if (i < NPTS) {
        const uint4 pw = ((const uint4*)packed)[i];
        const u32 p0 = pw.x, p1 = pw.y, p2 = pw.z, p3 = pw.w;
        const int   skipk = skipk_ptr[0];
        const float minx = minv[0], miny = minv[1];
        const float rx = rangev[0], ry = rangev[1];
        const float2 xyv = ((const float2*)xy0)[i];
        float x = xyv.x, y = xyv.y, c = c0[i];
        #pragma unroll
        for (int k = 0; k < KSTEPS; ++k) {
            const int idx = GETIDX(k);
            int xb, yb; bool inb;
            FLAME_STEP(idx, k);
            if (inb) {
                int pi = (int)__fadd_rn(__fmul_rn(c, 999.0f), 0.0005f);
                pi = min(max(pi, 0), FID - 1);
                const u32 r = (((u32)(xb << 10 | yb)) << 10) | (u32)pi;
                const u32 pos = atomicAdd(&s_cur[r >> 21], 1u);
                records[pos] = r;
            }
        }
    }
}

// ---------------------------------------------------------------------------
// K4: per-chunk LDS tile accumulation, 2048-px tile (32 KB) + 512 threads
// -> 4 blocks/CU, 32 waves/CU. Channels packed 2-per-u64 ds_add.
// ---------------------------------------------------------------------------
__global__ __launch_bounds__(512) void k_accum(
    const u32* __restrict__ pal_u32,
    const u32* __restrict__ totals, const u32* __restrict__ bases,
    const u32* __restrict__ mm, const u32* __restrict__ wstart,
    const u32* __restrict__ records,
    u32* __restrict__ partials)
{
    __shared__ u64 tile[BKTPX * 2];     // 32 KB
    __shared__ u32 s_ws[NBKT + 1];
    const int tid = threadIdx.x, w = blockIdx.x;

    if (tid <= NBKT) s_ws[tid] = wstart[tid];
    __syncthreads();
    if ((u32)w >= s_ws[NBKT]) return;   // uniform per block

    // largest b with wstart[b] <= w
    int b = 0;
    #pragma unroll
    for (int step = 256; step; step >>= 1)
        if (b + step <= NBKT - 1 && s_ws[b + step] <= (u32)w) b += step;

    for (int t = tid; t < BKTPX * 2; t += 512) tile[t] = 0ull;
    __syncthreads();

    const u32 cnt = totals[b], m = mm[b], cch = (u32)w - s_ws[b];
    const u32 rs = bases[b] + (u32)(((u64)cnt * cch) / m);
    const u32 re = bases[b] + (u32)(((u64)cnt * (cch + 1)) / m);

    const u64* pal_u64 = (const u64*)pal_u32;
    for (u32 j = rs + tid; j < re; j += 512) {
        const u32 r = records[j];
        const u32 local = (r >> 10) & (BKTPX - 1);
        const u32 pal = r & 1023u;
        const u64 w0 = pal_u64[pal * 2 + 0];
        const u64 w1 = pal_u64[pal * 2 + 1];
        atomicAdd(&tile[local * 2 + 0], w0);
        atomicAdd(&tile[local * 2 + 1], w1);
    }
    __syncthreads();

    uint4* dst = (uint4*)(partials + (size_t)w * BKTPX * 4);
    const uint4* src = (const uint4*)tile;
    for (int t = tid; t < BKTPX; t += 512) dst[t] = src[t];
}

// ---------------------------------------------------------------------------
// K5: sum partial tiles per bucket, unpack, add raw_image, write CHW out.
// ---------------------------------------------------------------------------
__global__ __launch_bounds__(256) void k_final(
    const u32* __restrict__ partials, const u32* __restrict__ wstart,
    const float* __restrict__ raw, float* __restrict__ out)
{
    const int p = blockIdx.x * 256 + threadIdx.x;
    const int b = p >> 11, local = p & (BKTPX - 1);
    u32 a0 = 0, a1 = 0, a2 = 0, a3 = 0;
    const u32 w0 = wstart[b], w1 = wstart[b + 1];
    for (u32 w = w0; w < w1; ++w) {
        const uint4 v = ((const uint4*)partials)[(size_t)w * BKTPX + local];
        a0 += v.x; a1 += v.y; a2 += v.z; a3 += v.w;
    }
    out[0*(size_t)HW + p] = __fadd_rn(raw[0*(size_t)HW + p], __fmul_rn((float)a0, FPINV));
    out[1*(size_t)HW + p] = __fadd_rn(raw[1*(size_t)HW + p], __fmul_rn((float)a1, FPINV));
    out[2*(size_t)HW + p] = __fadd_rn(raw[2*(size_t)HW + p], __fmul_rn((float)a2, FPINV));
    out[3*(size_t)HW + p] = __fadd_rn(raw[3*(size_t)HW + p], __fmul_rn((float)a3, FPINV));
}

// ---------------------------------------------------------------------------
// Fallback (ws too small): packed u64 global atomics (round-3 path).
// ---------------------------------------------------------------------------
__global__ __launch_bounds__(256) void flame_accum_packed(
    const float* __restrict__ palette,
    const float* __restrict__ Amat, const float* __restrict__ bvec,
    const float* __restrict__ fcolor,
    const float* __restrict__ xy0, const float* __restrict__ c0,
    const float* __restrict__ minv, const float* __restrict__ rangev,
    const int* __restrict__ fn_idx, const int* __restrict__ skipk_ptr,
    u64* __restrict__ ws)
{
    __shared__ __align__(16) float s_pal[FID * 4];
    __shared__ float s_tab[NF * 8];
    for (int t = threadIdx.x; t < FID; t += 256)
        ((float4*)s_pal)[t] = ((const float4*)palette)[t];
    LOAD_TABLES();
    __syncthreads();

    const int i = blockIdx.x * 256 + threadIdx.x;
    if (i >= NPTS) return;
    const int   skipk = skipk_ptr[0];
    const float minx = minv[0], miny = minv[1];
    const float rx = rangev[0], ry = rangev[1];
    const float2 xyv = ((const float2*)xy0)[i];
    float x = xyv.x, y = xyv.y, c = c0[i];
    for (int k = 0; k < KSTEPS; ++k) {
        const int idx = fn_idx[(size_t)k * NPTS + i];
        int xb, yb; bool inb;
        FLAME_STEP(idx, k);
        if (inb) {
            int pi = (int)__fadd_rn(__fmul_rn(c, 999.0f), 0.0005f);
            pi = min(max(pi, 0), FID - 1);
            const float4 col = *(const float4*)&s_pal[pi * 4];
            const u32 u0 = __float2uint_rn(__fmul_rn(col.x, FPSCALE));
            const u32 u1 = __float2uint_rn(__fmul_rn(col.y, FPSCALE));
            const u32 u2 = __float2uint_rn(__fmul_rn(col.z, FPSCALE));
            const u32 u3 = __float2uint_rn(__fmul_rn(col.w, FPSCALE));
            u64* p = ws + ((size_t)xb * IMG_W + yb) * 2;
            atomicAdd(p + 0, (u64)u0 | ((u64)u1 << 32));
            atomicAdd(p + 1, (u64)u2 | ((u64)u3 << 32));
        }
    }
}

__global__ __launch_bounds__(256) void reduce_packed(
    const u64* __restrict__ ws, const float* __restrict__ raw_image,
    float* __restrict__ out)
{
    const int p = blockIdx.x * 256 + threadIdx.x;
    if (p >= HW) return;
    const u64 w0 = ws[(size_t)p * 2 + 0];
    const u64 w1 = ws[(size_t)p * 2 + 1];
    out[0*(size_t)HW+p] = raw_image[0*(size_t)HW+p] + (float)(u32)(w0 & 0xffffffffull) * FPINV;
    out[1*(size_t)HW+p] = raw_image[1*(size_t)HW+p] + (float)(u32)(w0 >> 32)           * FPINV;
    out[2*(size_t)HW+p] = raw_image[2*(size_t)HW+p] + (float)(u32)(w1 & 0xffffffffull) * FPINV;
    out[3*(size_t)HW+p] = raw_image[3*(size_t)HW+p] + (float)(u32)(w1 >> 32)           * FPINV;
}

extern "C" void kernel_launch(void* const* d_in, const int* in_sizes, int n_in,
                              void* d_out, int out_size, void* d_ws, size_t ws_size,
                              hipStream_t stream) {
    const float* raw_image = (const float*)d_in[0];
    const float* palette   = (const float*)d_in[1];
    const float* A         = (const float*)d_in[2];
    const float* b         = (const float*)d_in[3];
    const float* fcolor    = (const float*)d_in[4];
    const float* xy0       = (const float*)d_in[5];
    const float* c0        = (const float*)d_in[6];
    const float* minv      = (const float*)d_in[7];
    const float* rangev    = (const float*)d_in[8];
    const int*   fn_idx    = (const int*)d_in[9];
    const int*   skipk     = (const int*)d_in[10];
    float* img = (float*)d_out;

    // ws layout (u32 units)
    u32* ws = (u32*)d_ws;
    u32* counts   = ws;                                  // NB*NBKT
    u32* prefix   = counts + (size_t)NB * NBKT;          // NB*NBKT
    u32* totals   = prefix + (size_t)NB * NBKT;          // NBKT
    u32* bases    = totals + NBKT;                       // NBKT
    u32* mm       = bases + NBKT;                        // NBKT
    u32* wstart   = mm + NBKT;                           // NBKT+1 (pad 1024)
    u32* pal_u32  = wstart + 1024;                       // 4096 (u64-aligned)
    u32* records  = pal_u32 + 4096;                      // NPTS*KSTEPS
    u32* partials = records + (size_t)NPTS * KSTEPS;     // K5G*BKTPX*4 (32MB)
    // packed fn_idx nibbles (16 MB) alias the FRONT of partials: packed is
    // dead once k_emit finishes; partials are written only in k_accum,
    // which is stream-ordered after k_emit.
    u32* packed   = partials;                            // NPTS*4 (aliased)
    const size_t need_u32 = (size_t)(partials - ws) + (size_t)K5G * BKTPX * 4;
    const size_t NEED = need_u32 * sizeof(u32);          // ~178 MB

    if (ws_size >= NEED) {
        k_pack_count<<<dim3(NB), 256, 0, stream>>>(A, b, fcolor, xy0, c0,
                                                   minv, rangev, fn_idx, skipk,
                                                   packed, counts);
        k_scanblocks<<<dim3(NBKT), 256, 0, stream>>>(counts, prefix, totals);
        k_meta<<<dim3(1), 512, 0, stream>>>(palette, totals, bases, mm, wstart,
                                            pal_u32);
        k_emit<<<dim3(NB), 256, 0, stream>>>(A, b, fcolor, xy0, c0, minv,
                                             rangev, packed, skipk, prefix,
                                             bases, records);
        k_accum<<<dim3(K5G), 512, 0, stream>>>(pal_u32, totals, bases, mm,
                                               wstart, records, partials);
        k_final<<<dim3(HW / 256), 256, 0, stream>>>(partials, wstart,
                                                    raw_image, img);
    } else {
        const size_t need2 = (size_t)HW * 2 * sizeof(u64);
        hipMemsetAsync(d_ws, 0, need2, stream);
        flame_accum_packed<<<dim3(NB), 256, 0, stream>>>(
            palette, A, b, fcolor, xy0, c0, minv, rangev, fn_idx, skipk,
            (u64*)d_ws);
        reduce_packed<<<dim3((HW + 255) / 256), 256, 0, stream>>>(
            (const u64*)d_ws, raw_image, img);
    }
}

// Round 9
// 211.121 us; speedup vs baseline: 17.2144x; 1.1511x over previous
//
#include <hip/hip_runtime.h>

typedef unsigned int u32;
typedef unsigned long long u64;

#define NPTS   1000000
#define KSTEPS 32
#define NF     8
#define IMG_H  1024
#define IMG_W  1024
#define FID    1000
#define HW     (IMG_H * IMG_W)
#define NB     3907            // ceil(NPTS/256)
#define NBKT   512             // bucket = pixel >> 11  (2 image rows)
#define BKTPX  2048            // pixels per bucket
#define K5G    1024            // accumulate workgroups (>= 512 + 508)
#define FPSCALE 4194304.0f     // 2^22 fixed point; capacity 1024 > max sum 488
#define FPINV   (1.0f / 4194304.0f)

// Extract step K's function index from packed nibble words p0..p3.
#define GETIDX(K)                                                              \
    ((int)(((((K) >> 3) == 0 ? p0 : ((K) >> 3) == 1 ? p1                       \
            : ((K) >> 3) == 2 ? p2 : p3) >> (((K) & 7) * 4)) & 7u))

// One chaos-game step, numpy-exact (no FMA contraction). Scalar LDS table
// reads: 8 distinct rows max -> broadcast/2-way aliasing (free on CDNA4).
#define FLAME_STEP(IDX, K)                                                     \
  {                                                                            \
    const float a00 = s_tab[(IDX)*8+0], a01 = s_tab[(IDX)*8+1];                \
    const float a10 = s_tab[(IDX)*8+2], a11 = s_tab[(IDX)*8+3];                \
    const float b0  = s_tab[(IDX)*8+4], b1  = s_tab[(IDX)*8+5];                \
    const float fc  = s_tab[(IDX)*8+6];                                        \
    const float nx = __fadd_rn(__fadd_rn(__fmul_rn(a00,x),__fmul_rn(a01,y)),b0);\
    const float ny = __fadd_rn(__fadd_rn(__fmul_rn(a10,x),__fmul_rn(a11,y)),b1);\
    x = nx; y = ny;                                                            \
    c = __fmul_rn(__fadd_rn(c, fc), 0.5f);                                     \
    xb = (int)__fmul_rn(__fsub_rn(x, minx), rx);                               \
    yb = (int)__fmul_rn(__fsub_rn(y, miny), ry);                               \
    inb = (xb >= 0) & (xb < IMG_W) & (yb >= 0) & (yb < IMG_H) & ((K) >= skipk);\
  }

#define LOAD_TABLES()                                                          \
    if (threadIdx.x < NF) {                                                    \
        const int f = threadIdx.x;                                             \
        s_tab[f*8+0] = Amat[f*4+0]; s_tab[f*8+1] = Amat[f*4+1];                \
        s_tab[f*8+2] = Amat[f*4+2]; s_tab[f*8+3] = Amat[f*4+3];                \
        s_tab[f*8+4] = bvec[f*2+0]; s_tab[f*8+5] = bvec[f*2+1];                \
        s_tab[f*8+6] = fcolor[f];   s_tab[f*8+7] = 0.0f;                       \
    }

// ---------------------------------------------------------------------------
// K1: pack fn_idx nibbles (32 INDEPENDENT coalesced loads) + flame +
// per-(block,bucket) hit counts.
// ---------------------------------------------------------------------------
__global__ __launch_bounds__(256) void k_pack_count(
    const float* __restrict__ Amat, const float* __restrict__ bvec,
    const float* __restrict__ fcolor,
    const float* __restrict__ xy0, const float* __restrict__ c0,
    const float* __restrict__ minv, const float* __restrict__ rangev,
    const int* __restrict__ fn_idx, const int* __restrict__ skipk_ptr,
    u32* __restrict__ packed, u32* __restrict__ counts)
{
    __shared__ u32 s_cnt[NBKT];
    __shared__ float s_tab[NF * 8];
    s_cnt[threadIdx.x] = 0u;
    s_cnt[threadIdx.x + 256] = 0u;
    LOAD_TABLES();
    __syncthreads();

    const int i = blockIdx.x * 256 + threadIdx.x;
    if (i < NPTS) {
        u32 p0 = 0, p1 = 0, p2 = 0, p3 = 0;
        #pragma unroll
        for (int k = 0; k < 8; ++k)
            p0 |= ((u32)fn_idx[(size_t)k * NPTS + i] & 7u) << (k * 4);
        #pragma unroll
        for (int k = 0; k < 8; ++k)
            p1 |= ((u32)fn_idx[(size_t)(k + 8) * NPTS + i] & 7u) << (k * 4);
        #pragma unroll
        for (int k = 0; k < 8; ++k)
            p2 |= ((u32)fn_idx[(size_t)(k + 16) * NPTS + i] & 7u) << (k * 4);
        #pragma unroll
        for (int k = 0; k < 8; ++k)
            p3 |= ((u32)fn_idx[(size_t)(k + 24) * NPTS + i] & 7u) << (k * 4);

        ((uint4*)packed)[i] = make_uint4(p0, p1, p2, p3);

        const int   skipk = skipk_ptr[0];
        const float minx = minv[0], miny = minv[1];
        const float rx = rangev[0], ry = rangev[1];
        const float2 xyv = ((const float2*)xy0)[i];
        float x = xyv.x, y = xyv.y, c = c0[i];
        #pragma unroll
        for (int k = 0; k < KSTEPS; ++k) {
            const int idx = GETIDX(k);
            int xb, yb; bool inb;
            FLAME_STEP(idx, k);
            if (inb) atomicAdd(&s_cnt[xb >> 1], 1u);   // bucket = pixel>>11 = xb>>1
        }
    }
    __syncthreads();
    counts[(size_t)blockIdx.x * NBKT + threadIdx.x] = s_cnt[threadIdx.x];
    counts[(size_t)blockIdx.x * NBKT + threadIdx.x + 256] = s_cnt[threadIdx.x + 256];
}

// ---------------------------------------------------------------------------
// K2a: per-bucket exclusive prefix over blocks; totals per bucket.
// ---------------------------------------------------------------------------
__global__ __launch_bounds__(256) void k_scanblocks(
    const u32* __restrict__ counts, u32* __restrict__ prefix,
    u32* __restrict__ totals)
{
    const int b = blockIdx.x, tid = threadIdx.x;
    u32 v[16]; u32 s = 0;
    #pragma unroll
    for (int j = 0; j < 16; ++j) {
        const int row = tid * 16 + j;
        v[j] = (row < NB) ? counts[(size_t)row * NBKT + b] : 0u;
        s += v[j];
    }
    __shared__ u32 sc[256];
    sc[tid] = s; __syncthreads();
    #pragma unroll
    for (int o = 1; o < 256; o <<= 1) {
        u32 t = (tid >= o) ? sc[tid - o] : 0u;
        __syncthreads();
        sc[tid] += t;
        __syncthreads();
    }
    u32 run = sc[tid] - s;   // exclusive
    #pragma unroll
    for (int j = 0; j < 16; ++j) {
        const int row = tid * 16 + j;
        if (row < NB) prefix[(size_t)row * NBKT + b] = run;
        run += v[j];
    }
    if (tid == 255) totals[b] = sc[255];
}

// ---------------------------------------------------------------------------
// K2b: bucket bases, chunk counts m[b], wstart scan, fixed-point palette.
// ---------------------------------------------------------------------------
__global__ __launch_bounds__(512) void k_meta(
    const float* __restrict__ palette,
    const u32* __restrict__ totals,
    u32* __restrict__ bases, u32* __restrict__ mm, u32* __restrict__ wstart,
    u32* __restrict__ pal_u32)
{
    __shared__ u32 sc[NBKT];
    const int tid = threadIdx.x;

    for (int t = tid; t < FID * 4; t += 512)
        pal_u32[t] = __float2uint_rn(__fmul_rn(palette[t], FPSCALE));

    const u32 t0 = totals[tid];
    sc[tid] = t0; __syncthreads();
    #pragma unroll
    for (int o = 1; o < NBKT; o <<= 1) {
        u32 v = (tid >= o) ? sc[tid - o] : 0u;
        __syncthreads(); sc[tid] += v; __syncthreads();
    }
    const u32 total = sc[NBKT - 1];
    bases[tid] = sc[tid] - t0;

    const u32 m = 1u + (total ? (u32)((508ull * t0) / total) : 0u);
    mm[tid] = m;
    __syncthreads(); sc[tid] = m; __syncthreads();
    #pragma unroll
    for (int o = 1; o < NBKT; o <<= 1) {
        u32 v = (tid >= o) ? sc[tid - o] : 0u;
        __syncthreads(); sc[tid] += v; __syncthreads();
    }
    wstart[tid] = sc[tid] - m;
    if (tid == NBKT - 1) wstart[NBKT] = sc[NBKT - 1];
}

// ---------------------------------------------------------------------------
// K3: flame from PACKED indices; records staged in LDS bucket-sorted via
// local cursors (counts-row scan), then written per-bucket with aligned
// uint4 stores -> line-dense global writes (kills the 2.2x write amp).
// ---------------------------------------------------------------------------
__global__ __launch_bounds__(256) void k_emit(
    const float* __restrict__ Amat, const float* __restrict__ bvec,
    const float* __restrict__ fcolor,
    const float* __restrict__ xy0, const float* __restrict__ c0,
    const float* __restrict__ minv, const float* __restrict__ rangev,
    const u32* __restrict__ packed, const int* __restrict__ skipk_ptr,
    const u32* __restrict__ prefix, const u32* __restrict__ bases,
    const u32* __restrict__ counts,
    u32* __restrict__ records)
{
    __shared__ u32 s_rec[256 * KSTEPS];   // 32 KB: all of this block's records
    __shared__ u32 s_cur[NBKT];           // local cursors (then: lp[b+1])
    __shared__ u32 s_gbase[NBKT];         // global segment base per bucket
    __shared__ u32 s_scan[256];
    __shared__ float s_tab[NF * 8];
    const int tid = threadIdx.x;

    // Per-block bucket counts (pairs for 2-per-thread scan) + global bases.
    const uint2 cc = ((const uint2*)(counts + (size_t)blockIdx.x * NBKT))[tid];
    const uint2 bb = ((const uint2*)bases)[tid];
    const uint2 pp = ((const uint2*)(prefix + (size_t)blockIdx.x * NBKT))[tid];
    s_gbase[2 * tid]     = bb.x + pp.x;
    s_gbase[2 * tid + 1] = bb.y + pp.y;

    const u32 psum = cc.x + cc.y;
    s_scan[tid] = psum; __syncthreads();
    #pragma unroll
    for (int o = 1; o < 256; o <<= 1) {
        u32 t = (tid >= o) ? s_scan[tid - o] : 0u;
        __syncthreads();
        s_scan[tid] += t;
        __syncthreads();
    }
    const u32 excl = s_scan[tid] - psum;          // local_prefix[2*tid]
    s_cur[2 * tid]     = excl;
    s_cur[2 * tid + 1] = excl + cc.x;
    LOAD_TABLES();
    __syncthreads();

    // Phase A: flame -> LDS records via local cursors.
    const int i = blockIdx.x * 256 + tid;
    if (i < NPTS) {
        const uint4 pw = ((const uint4*)packed)[i];
        const u32 p0 = pw.x, p1 = pw.y, p2 = pw.z, p3 = pw.w;
        const int   skipk = skipk_ptr[0];
        const float minx = minv[0], miny = minv[1];
        const float rx = rangev[0], ry = rangev[1];
        const float2 xyv = ((const float2*)xy0)[i];
        float x = xyv.x, y = xyv.y, c = c0[i];
        #pragma unroll
        for (int k = 0; k < KSTEPS; ++k) {
            const int idx = GETIDX(k);
            int xb, yb; bool inb;
            FLAME_STEP(idx, k);
            if (inb) {
                int pi = (int)__fadd_rn(__fmul_rn(c, 999.0f), 0.0005f);
                pi = min(max(pi, 0), FID - 1);
                const u32 r = (((u32)(xb << 10 | yb)) << 10) | (u32)pi;
                const u32 pos = atomicAdd(&s_cur[r >> 21], 1u);
                s_rec[pos] = r;
            }
        }
    }
    __syncthreads();

    // Phase B: per-bucket segment copy to global, uint4-vectorized.
    // After phase A: s_cur[b] == local_prefix[b] + cnt[b] == local_prefix[b+1].
    for (int b = tid; b < NBKT; b += 256) {
        const u32 lp = (b == 0) ? 0u : s_cur[b - 1];
        const u32 ce = s_cur[b];
        u32 dst = s_gbase[b];
        u32 j = lp;
        while (j < ce && (dst & 3u)) records[dst++] = s_rec[j++];
        for (; j + 4 <= ce; j += 4, dst += 4)
            *(uint4*)(records + dst) =
                make_uint4(s_rec[j], s_rec[j+1], s_rec[j+2], s_rec[j+3]);
        while (j < ce) records[dst++] = s_rec[j++];
    }
}

// ---------------------------------------------------------------------------
// K4: per-chunk LDS tile accumulation, 2048-px tile (32 KB) + 512 threads.
// ---------------------------------------------------------------------------
__global__ __launch_bounds__(512) void k_accum(
    const u32* __restrict__ pal_u32,
    const u32* __restrict__ totals, const u32* __restrict__ bases,
    const u32* __restrict__ mm, const u32* __restrict__ wstart,
    const u32* __restrict__ records,
    u32* __restrict__ partials)
{
    __shared__ u64 tile[BKTPX * 2];     // 32 KB
    __shared__ u32 s_ws[NBKT + 1];
    const int tid = threadIdx.x, w = blockIdx.x;

    if (tid <= NBKT) s_ws[tid] = wstart[tid];
    __syncthreads();
    if ((u32)w >= s_ws[NBKT]) return;   // uniform per block

    int b = 0;
    #pragma unroll
    for (int step = 256; step; step >>= 1)
        if (b + step <= NBKT - 1 && s_ws[b + step] <= (u32)w) b += step;

    for (int t = tid; t < BKTPX * 2; t += 512) tile[t] = 0ull;
    __syncthreads();

    const u32 cnt = totals[b], m = mm[b], cch = (u32)w - s_ws[b];
    const u32 rs = bases[b] + (u32)(((u64)cnt * cch) / m);
    const u32 re = bases[b] + (u32)(((u64)cnt * (cch + 1)) / m);

    const u64* pal_u64 = (const u64*)pal_u32;
    for (u32 j = rs + tid; j < re; j += 512) {
        const u32 r = records[j];
        const u32 local = (r >> 10) & (BKTPX - 1);
        const u32 pal = r & 1023u;
        const u64 w0 = pal_u64[pal * 2 + 0];
        const u64 w1 = pal_u64[pal * 2 + 1];
        atomicAdd(&tile[local * 2 + 0], w0);
        atomicAdd(&tile[local * 2 + 1], w1);
    }
    __syncthreads();

    uint4* dst = (uint4*)(partials + (size_t)w * BKTPX * 4);
    const uint4* src = (const uint4*)tile;
    for (int t = tid; t < BKTPX; t += 512) dst[t] = src[t];
}

// ---------------------------------------------------------------------------
// K5: sum partial tiles per bucket, unpack, add raw_image, write CHW out.
// ---------------------------------------------------------------------------
__global__ __launch_bounds__(256) void k_final(
    const u32* __restrict__ partials, const u32* __restrict__ wstart,
    const float* __restrict__ raw, float* __restrict__ out)
{
    const int p = blockIdx.x * 256 + threadIdx.x;
    const int b = p >> 11, local = p & (BKTPX - 1);
    u32 a0 = 0, a1 = 0, a2 = 0, a3 = 0;
    const u32 w0 = wstart[b], w1 = wstart[b + 1];
    for (u32 w = w0; w < w1; ++w) {
        const uint4 v = ((const uint4*)partials)[(size_t)w * BKTPX + local];
        a0 += v.x; a1 += v.y; a2 += v.z; a3 += v.w;
    }
    out[0*(size_t)HW + p] = __fadd_rn(raw[0*(size_t)HW + p], __fmul_rn((float)a0, FPINV));
    out[1*(size_t)HW + p] = __fadd_rn(raw[1*(size_t)HW + p], __fmul_rn((float)a1, FPINV));
    out[2*(size_t)HW + p] = __fadd_rn(raw[2*(size_t)HW + p], __fmul_rn((float)a2, FPINV));
    out[3*(size_t)HW + p] = __fadd_rn(raw[3*(size_t)HW + p], __fmul_rn((float)a3, FPINV));
}

// ---------------------------------------------------------------------------
// Fallback (ws too small): packed u64 global atomics (round-3 path).
// ---------------------------------------------------------------------------
__global__ __launch_bounds__(256) void flame_accum_packed(
    const float* __restrict__ palette,
    const float* __restrict__ Amat, const float* __restrict__ bvec,
    const float* __restrict__ fcolor,
    const float* __restrict__ xy0, const float* __restrict__ c0,
    const float* __restrict__ minv, const float* __restrict__ rangev,
    const int* __restrict__ fn_idx, const int* __restrict__ skipk_ptr,
    u64* __restrict__ ws)
{
    __shared__ __align__(16) float s_pal[FID * 4];
    __shared__ float s_tab[NF * 8];
    for (int t = threadIdx.x; t < FID; t += 256)
        ((float4*)s_pal)[t] = ((const float4*)palette)[t];
    LOAD_TABLES();
    __syncthreads();

    const int i = blockIdx.x * 256 + threadIdx.x;
    if (i >= NPTS) return;
    const int   skipk = skipk_ptr[0];
    const float minx = minv[0], miny = minv[1];
    const float rx = rangev[0], ry = rangev[1];
    const float2 xyv = ((const float2*)xy0)[i];
    float x = xyv.x, y = xyv.y, c = c0[i];
    for (int k = 0; k < KSTEPS; ++k) {
        const int idx = fn_idx[(size_t)k * NPTS + i];
        int xb, yb; bool inb;
        FLAME_STEP(idx, k);
        if (inb) {
            int pi = (int)__fadd_rn(__fmul_rn(c, 999.0f), 0.0005f);
            pi = min(max(pi, 0), FID - 1);
            const float4 col = *(const float4*)&s_pal[pi * 4];
            const u32 u0 = __float2uint_rn(__fmul_rn(col.x, FPSCALE));
            const u32 u1 = __float2uint_rn(__fmul_rn(col.y, FPSCALE));
            const u32 u2 = __float2uint_rn(__fmul_rn(col.z, FPSCALE));
            const u32 u3 = __float2uint_rn(__fmul_rn(col.w, FPSCALE));
            u64* p = ws + ((size_t)xb * IMG_W + yb) * 2;
            atomicAdd(p + 0, (u64)u0 | ((u64)u1 << 32));
            atomicAdd(p + 1, (u64)u2 | ((u64)u3 << 32));
        }
    }
}

__global__ __launch_bounds__(256) void reduce_packed(
    const u64* __restrict__ ws, const float* __restrict__ raw_image,
    float* __restrict__ out)
{
    const int p = blockIdx.x * 256 + threadIdx.x;
    if (p >= HW) return;
    const u64 w0 = ws[(size_t)p * 2 + 0];
    const u64 w1 = ws[(size_t)p * 2 + 1];
    out[0*(size_t)HW+p] = raw_image[0*(size_t)HW+p] + (float)(u32)(w0 & 0xffffffffull) * FPINV;
    out[1*(size_t)HW+p] = raw_image[1*(size_t)HW+p] + (float)(u32)(w0 >> 32)           * FPINV;
    out[2*(size_t)HW+p] = raw_image[2*(size_t)HW+p] + (float)(u32)(w1 & 0xffffffffull) * FPINV;
    out[3*(size_t)HW+p] = raw_image[3*(size_t)HW+p] + (float)(u32)(w1 >> 32)           * FPINV;
}

extern "C" void kernel_launch(void* const* d_in, const int* in_sizes, int n_in,
                              void* d_out, int out_size, void* d_ws, size_t ws_size,
                              hipStream_t stream) {
    const float* raw_image = (const float*)d_in[0];
    const float* palette   = (const float*)d_in[1];
    const float* A         = (const float*)d_in[2];
    const float* b         = (const float*)d_in[3];
    const float* fcolor    = (const float*)d_in[4];
    const float* xy0       = (const float*)d_in[5];
    const float* c0        = (const float*)d_in[6];
    const float* minv      = (const float*)d_in[7];
    const float* rangev    = (const float*)d_in[8];
    const int*   fn_idx    = (const int*)d_in[9];
    const int*   skipk     = (const int*)d_in[10];
    float* img = (float*)d_out;

    // ws layout (u32 units)
    u32* ws = (u32*)d_ws;
    u32* counts   = ws;                                  // NB*NBKT
    u32* prefix   = counts + (size_t)NB * NBKT;          // NB*NBKT
    u32* totals   = prefix + (size_t)NB * NBKT;          // NBKT
    u32* bases    = totals + NBKT;                       // NBKT
    u32* mm       = bases + NBKT;                        // NBKT
    u32* wstart   = mm + NBKT;                           // NBKT+1 (pad 1024)
    u32* pal_u32  = wstart + 1024;                       // 4096 (u64-aligned)
    u32* records  = pal_u32 + 4096;                      // NPTS*KSTEPS
    u32* partials = records + (size_t)NPTS * KSTEPS;     // K5G*BKTPX*4 (32MB)
    // packed fn_idx nibbles (16 MB) alias the FRONT of partials (dead after
    // k_emit; partials written only in k_accum, stream-ordered later).
    u32* packed   = partials;                            // NPTS*4 (aliased)
    const size_t need_u32 = (size_t)(partials - ws) + (size_t)K5G * BKTPX * 4;
    const size_t NEED = need_u32 * sizeof(u32);          // ~178 MB

    if (ws_size >= NEED) {
        k_pack_count<<<dim3(NB), 256, 0, stream>>>(A, b, fcolor, xy0, c0,
                                                   minv, rangev, fn_idx, skipk,
                                                   packed, counts);
        k_scanblocks<<<dim3(NBKT), 256, 0, stream>>>(counts, prefix, totals);
        k_meta<<<dim3(1), 512, 0, stream>>>(palette, totals, bases, mm, wstart,
                                            pal_u32);
        k_emit<<<dim3(NB), 256, 0, stream>>>(A, b, fcolor, xy0, c0, minv,
                                             rangev, packed, skipk, prefix,
                                             bases, counts, records);
        k_accum<<<dim3(K5G), 512, 0, stream>>>(pal_u32, totals, bases, mm,
                                               wstart, records, partials);
        k_final<<<dim3(HW / 256), 256, 0, stream>>>(partials, wstart,
                                                    raw_image, img);
    } else {
        const size_t need2 = (size_t)HW * 2 * sizeof(u64);
        hipMemsetAsync(d_ws, 0, need2, stream);
        flame_accum_packed<<<dim3(NB), 256, 0, stream>>>(
            palette, A, b, fcolor, xy0, c0, minv, rangev, fn_idx, skipk,
            (u64*)d_ws);
        reduce_packed<<<dim3((HW + 255) / 256), 256, 0, stream>>>(
            (const u64*)d_ws, raw_image, img);
    }
}